// Round 9
// baseline (373.240 us; speedup 1.0000x reference)
//
#include <hip/hip_runtime.h>
#include <hip/hip_bf16.h>

typedef __hip_bfloat16 bf16;

typedef short bf16x8 __attribute__((ext_vector_type(8)));   // 8 bf16 (4 VGPRs), MFMA A/B frag
typedef float f32x4  __attribute__((ext_vector_type(4)));   // MFMA C/D frag
typedef float f32x2  __attribute__((ext_vector_type(2)));

__device__ __forceinline__ float bflo(unsigned v){ union{unsigned u; float f;} c; c.u = v << 16; return c.f; }
__device__ __forceinline__ float bfhi(unsigned v){ union{unsigned u; float f;} c; c.u = v & 0xffff0000u; return c.f; }

// float -> fp8 e4m3 (OCP on gfx950), single byte
__device__ __forceinline__ unsigned char f32_to_fp8(float v){
  return (unsigned char)(__builtin_amdgcn_cvt_pk_fp8_f32(v, v, 0, false) & 0xFF);
}

// ---------------------------------------------------------------------------
// prep_kernel: horizontal fusion of all independent setup work.
// Regions by blockIdx.x:
//   [0,128)        transpose W0  (128x1024 -> Bt0)
//   [128,160)      transpose sW0 (128x256  -> Bt0+1024*128)
//   [160,416)      transpose W1  (256x1024 -> Bt1)
//   [416,b4)       hist: deg[dst]++
//   [b4,b5)        edgecopy: out1[i] = float(ei[i])
//   [b5,b6)        proj128: p0[node] = u0^T x[node]
// ---------------------------------------------------------------------------
__device__ __forceinline__ void dev_transpose32(
    const bf16* __restrict__ B, bf16* __restrict__ Bt, int K, int NC,
    int bx, int by, int t, bf16 (*tile)[33])
{
  const int tx = t & 31, ty = t >> 5;   // ty 0..7
  #pragma unroll
  for (int i = 0; i < 32; i += 8)
    tile[ty + i][tx] = B[(size_t)(by * 32 + ty + i) * NC + bx * 32 + tx];
  __syncthreads();
  #pragma unroll
  for (int i = 0; i < 32; i += 8)
    Bt[(size_t)(bx * 32 + ty + i) * K + by * 32 + tx] = tile[tx][ty + i];
}

__global__ __launch_bounds__(256) void prep_kernel(
    const bf16* __restrict__ x, const int* __restrict__ ei,
    const bf16* __restrict__ W0, const bf16* __restrict__ sW0,
    const bf16* __restrict__ W1, const bf16* __restrict__ u0,
    bf16* __restrict__ Bt0, bf16* __restrict__ Bt1,
    int* __restrict__ deg, float* __restrict__ eout, float4* __restrict__ p0,
    int N, int E, int b4, int b5, int b6)
{
  __shared__ bf16 tile[32][33];
  const int bid = blockIdx.x;
  const int t   = threadIdx.x;

  if (bid < 128) {                 // W0: 128x1024, grid 32x4
    dev_transpose32(W0, Bt0, 128, 1024, bid & 31, bid >> 5, t, tile);
  } else if (bid < 160) {          // sW0: 128x256, grid 8x4
    const int lb = bid - 128;
    dev_transpose32(sW0, Bt0 + 1024 * 128, 128, 256, lb & 7, lb >> 3, t, tile);
  } else if (bid < 416) {          // W1: 256x1024, grid 32x8
    const int lb = bid - 160;
    dev_transpose32(W1, Bt1, 256, 1024, lb & 31, lb >> 5, t, tile);
  } else if (bid < b4) {           // hist
    const int e = (bid - 416) * 256 + t;
    if (e < E) atomicAdd(deg + ei[E + e], 1);
  } else if (bid < b5) {           // edgecopy (output 1)
    const int i = (bid - b4) * 256 + t;
    if (i < 2 * E) eout[i] = (float)ei[i];
  } else {                          // proj128: 4 nodes per block
    const int node = (bid - b5) * 4 + (t >> 6);
    if (node >= N) return;
    const int lane = t & 63;
    const unsigned xv = ((const unsigned*)(x + (size_t)node * 128))[lane];
    const float d0 = bflo(xv), d1 = bfhi(xv);
    const uint4 uv = *(const uint4*)(u0 + (size_t)lane * 8);
    float t0 = d0 * bflo(uv.x) + d1 * bflo(uv.z);
    float t1 = d0 * bfhi(uv.x) + d1 * bfhi(uv.z);
    float t2 = d0 * bflo(uv.y) + d1 * bflo(uv.w);
    float t3 = d0 * bfhi(uv.y) + d1 * bfhi(uv.w);
    #pragma unroll
    for (int off = 32; off > 0; off >>= 1) {
      t0 += __shfl_xor(t0, off);
      t1 += __shfl_xor(t1, off);
      t2 += __shfl_xor(t2, off);
      t3 += __shfl_xor(t3, off);
    }
    if (lane == 0) p0[node] = make_float4(t0, t1, t2, t3);
  }
}

// ---------------------------------------------------------------------------
// MFMA GEMM: C[M x NC] = A[M x K](bf16, row-major) @ Bt[NC x K](bf16, n-major)
// 128x128 block tile, 4 waves (2x2), each wave 4x4 of 16x16x32 MFMA, BK=32.
// col0 <  nsplit -> fp8 byte store to Cy, HEAD-INTERLEAVED:
//                   Cy[row*1024 + (col&255)*4 + (col>>8)]   (y[node][ch][head])
// col0 >= nsplit -> f32 store to Cs (ld=lds_) + bias (normal layout).
// ---------------------------------------------------------------------------
__global__ __launch_bounds__(256) void gemm_mfma_kernel(
    const bf16* __restrict__ A, const bf16* __restrict__ Bt,
    int M, int K,
    unsigned char* __restrict__ Cy, int nsplit,
    float* __restrict__ Cs, const bf16* __restrict__ sbias, int lds_)
{
  constexpr int LDA = 40;                       // padded LDS row stride (bf16 elems), 80B
  __shared__ __align__(16) bf16 As[128 * LDA];  // 10240 B
  __shared__ __align__(16) bf16 Bs[128 * LDA];  // 10240 B

  const int tid  = threadIdx.x;
  const int row0 = blockIdx.x * 128;
  const int col0 = blockIdx.y * 128;
  const int lane = tid & 63;
  const int wave = tid >> 6;
  const int wm   = wave & 1, wn = wave >> 1;
  const int ln   = lane & 15, quad = lane >> 4;

  f32x4 acc[4][4] = {};

  for (int k0 = 0; k0 < K; k0 += 32) {
    #pragma unroll
    for (int rep = 0; rep < 2; ++rep) {
      const int cs = tid + rep * 256;
      const int r  = cs >> 2;
      const int kp = (cs & 3) << 3;
      const int gr = min(row0 + r, M - 1);      // clamp: dup rows only feed unstored C rows
      const uint4 va = *(const uint4*)(A  + (size_t)gr * K        + k0 + kp);
      *(uint4*)(As + r * LDA + kp) = va;
      const uint4 vb = *(const uint4*)(Bt + (size_t)(col0 + r) * K + k0 + kp);
      *(uint4*)(Bs + r * LDA + kp) = vb;
    }
    __syncthreads();

    bf16x8 a[4], b[4];
    #pragma unroll
    for (int mi = 0; mi < 4; ++mi)
      a[mi] = *(const bf16x8*)(As + (wm * 64 + mi * 16 + ln) * LDA + quad * 8);
    #pragma unroll
    for (int ni = 0; ni < 4; ++ni)
      b[ni] = *(const bf16x8*)(Bs + (wn * 64 + ni * 16 + ln) * LDA + quad * 8);
    #pragma unroll
    for (int mi = 0; mi < 4; ++mi)
      #pragma unroll
      for (int ni = 0; ni < 4; ++ni)
        acc[mi][ni] = __builtin_amdgcn_mfma_f32_16x16x32_bf16(a[mi], b[ni], acc[mi][ni], 0, 0, 0);
    __syncthreads();
  }

  // epilogue: C[row=quad*4+r][col=ln] per 16x16 tile
  if (col0 < nsplit) {
    #pragma unroll
    for (int mi = 0; mi < 4; ++mi) {
      const int rbase = row0 + wm * 64 + mi * 16 + quad * 4;
      #pragma unroll
      for (int ni = 0; ni < 4; ++ni) {
        const int col = col0 + wn * 64 + ni * 16 + ln;
        const int ic  = (col & 255) * 4 + (col >> 8);   // head-interleaved byte position
        #pragma unroll
        for (int r = 0; r < 4; ++r) {
          const int gr = rbase + r;
          if (gr < M) Cy[(size_t)gr * 1024 + ic] = f32_to_fp8(acc[mi][ni][r]);
        }
      }
    }
  } else {
    const int cbase = col0 - nsplit;
    #pragma unroll
    for (int mi = 0; mi < 4; ++mi) {
      const int rbase = row0 + wm * 64 + mi * 16 + quad * 4;
      #pragma unroll
      for (int ni = 0; ni < 4; ++ni) {
        const int col = cbase + wn * 64 + ni * 16 + ln;
        const float bb = __bfloat162float(sbias[col]);
        #pragma unroll
        for (int r = 0; r < 4; ++r) {
          const int gr = rbase + r;
          if (gr < M) Cs[(size_t)gr * lds_ + col] = acc[mi][ni][r] + bb;
        }
      }
    }
  }
}

// ---------------------------------------------------------------------------
// scan + scatter (CSR build)
// ---------------------------------------------------------------------------
__global__ __launch_bounds__(256) void scan_kernel(
    const int* __restrict__ deg, int* __restrict__ rowptr, int N)
{
  __shared__ int part[256];
  const int t = threadIdx.x;
  const int chunk = (N + 255) / 256;
  const int start = t * chunk;
  const int stop  = min(start + chunk, N);
  int sum = 0;
  for (int j = start; j < stop; ++j) sum += deg[j];
  part[t] = sum;
  __syncthreads();
  for (int off = 1; off < 256; off <<= 1) {
    int v = (t >= off) ? part[t - off] : 0;
    __syncthreads();
    part[t] += v;
    __syncthreads();
  }
  int base = (t == 0) ? 0 : part[t - 1];
  for (int j = start; j < stop; ++j) { rowptr[j] = base; base += deg[j]; }
  if (t == 255) rowptr[N] = part[255];
}

__global__ __launch_bounds__(256) void scatter_kernel(
    const int* __restrict__ ei, const int* __restrict__ rowptr,
    int* __restrict__ cursor, int* __restrict__ ssrc, int E)
{
  const int e = (int)((unsigned)blockIdx.x * 256u + threadIdx.x);
  if (e >= E) return;
  const int src = ei[e];
  const int d   = ei[E + e];
  const int pp  = rowptr[d] + atomicAdd(cursor + d, 1);
  ssrc[pp] = src;
}

// ---------------------------------------------------------------------------
// Pass B v5: one block per dst node. Fused passA (q from p on the fly).
// Lane owns 4 channels (16B of the fp8 head-interleaved y row); 4 waves
// stride the edge list, unrolled x4 -> 16 row-gathers in flight per block.
// Optional fused next-projection: p_next[i] = u_next^T h0_row.
// ---------------------------------------------------------------------------
#define PB_CHUNK 64

template<bool OUT_FLOAT, bool SKIP_FLOAT>
__global__ __launch_bounds__(256) void passB_kernel(
    const int* __restrict__ rowptr, const int* __restrict__ ssrc,
    const float4* __restrict__ p, const unsigned char* __restrict__ y,
    const bf16* __restrict__ cvec, const bf16* __restrict__ bias,
    const float* __restrict__ skipf, const bf16* __restrict__ skipb,
    float* __restrict__ outf, bf16* __restrict__ outb,
    const bf16* __restrict__ u_next, float* __restrict__ p_next)
{
  __shared__ int    s_off[PB_CHUNK];
  __shared__ float4 s_q[PB_CHUNK];
  __shared__ float  red[4][256];

  const int i   = blockIdx.x;
  const int t   = threadIdx.x;
  const int g   = t >> 6;       // wave id
  const int l   = t & 63;       // lane: channels 4l..4l+3
  const int beg = rowptr[i], end = rowptr[i + 1];
  const int deg = end - beg;

  const float cc0 = __bfloat162float(cvec[0]), cc1 = __bfloat162float(cvec[1]);
  const float cc2 = __bfloat162float(cvec[2]), cc3 = __bfloat162float(cvec[3]);
  const float4 pd = p[i];

  f32x2 ap0 = {0.f, 0.f}, ap1 = {0.f, 0.f}, ap2 = {0.f, 0.f}, ap3 = {0.f, 0.f};

#define PB_BODY(EIDX)                                                          \
  {                                                                            \
    const int    off = s_off[EIDX];                                            \
    const float4 q   = s_q[EIDX];                                              \
    const uint4  v   = *(const uint4*)(y + (size_t)off + l * 16);              \
    f32x2 q01; q01.x = q.x; q01.y = q.y;                                       \
    f32x2 q23; q23.x = q.z; q23.y = q.w;                                       \
    ap0 += q01 * __builtin_amdgcn_cvt_pk_f32_fp8((int)v.x, false)              \
         + q23 * __builtin_amdgcn_cvt_pk_f32_fp8((int)v.x, true);              \
    ap1 += q01 * __builtin_amdgcn_cvt_pk_f32_fp8((int)v.y, false)              \
         + q23 * __builtin_amdgcn_cvt_pk_f32_fp8((int)v.y, true);              \
    ap2 += q01 * __builtin_amdgcn_cvt_pk_f32_fp8((int)v.z, false)              \
         + q23 * __builtin_amdgcn_cvt_pk_f32_fp8((int)v.z, true);              \
    ap3 += q01 * __builtin_amdgcn_cvt_pk_f32_fp8((int)v.w, false)              \
         + q23 * __builtin_amdgcn_cvt_pk_f32_fp8((int)v.w, true);              \
  }

  for (int c0 = 0; c0 < deg; c0 += PB_CHUNK) {
    const int cnt = min(PB_CHUNK, deg - c0);
    __syncthreads();
    if (t < cnt) {
      const int src = ssrc[beg + c0 + t];
      s_off[t] = src << 10;                        // byte offset of y row
      const float4 ps = p[src];                    // fused passA
      const float t0 = ps.x - pd.x + cc0;
      const float t1 = ps.y - pd.y + cc1;
      const float t2 = ps.z - pd.z + cc2;
      const float t3 = ps.w - pd.w + cc3;
      const float mx = fmaxf(fmaxf(t0, t1), fmaxf(t2, t3));
      const float e0 = __expf(t0 - mx), e1 = __expf(t1 - mx);
      const float e2 = __expf(t2 - mx), e3 = __expf(t3 - mx);
      const float inv = 1.f / (e0 + e1 + e2 + e3);
      s_q[t] = make_float4(e0 * inv, e1 * inv, e2 * inv, e3 * inv);
    }
    __syncthreads();

    int e = g;
    for (; e + 12 < cnt; e += 16) {          // 4 independent gathers in flight
      PB_BODY(e) PB_BODY(e + 4) PB_BODY(e + 8) PB_BODY(e + 12)
    }
    for (; e < cnt; e += 4) PB_BODY(e)
  }
#undef PB_BODY

  // cross-wave reduction: red[g][channel]
  __syncthreads();
  {
    float4 r;
    r.x = ap0.x + ap0.y; r.y = ap1.x + ap1.y;
    r.z = ap2.x + ap2.y; r.w = ap3.x + ap3.y;
    *(float4*)&red[g][l * 4] = r;
  }
  __syncthreads();

  const int ch = t;
  float acc = red[0][ch] + red[1][ch] + red[2][ch] + red[3][ch];

  // self loop: q = softmax(c)
  const float mx = fmaxf(fmaxf(cc0, cc1), fmaxf(cc2, cc3));
  const float e0 = __expf(cc0 - mx), e1 = __expf(cc1 - mx);
  const float e2 = __expf(cc2 - mx), e3 = __expf(cc3 - mx);
  const float inv = 1.f / (e0 + e1 + e2 + e3);
  const unsigned vi = *(const unsigned*)(y + (size_t)i * 1024 + ch * 4);
  const f32x2 li  = __builtin_amdgcn_cvt_pk_f32_fp8((int)vi, false);
  const f32x2 hii = __builtin_amdgcn_cvt_pk_f32_fp8((int)vi, true);
  acc += (e0 * li.x + e1 * li.y + e2 * hii.x + e3 * hii.y) * inv;

  const int idx = i * 256 + ch;
  float v = acc / (float)(deg + 1) + __bfloat162float(bias[ch]);
  v += SKIP_FLOAT ? skipf[idx] : __bfloat162float(skipb[idx]);
  v = fmaxf(v, 0.f);
  if (OUT_FLOAT) outf[idx] = v;
  else           outb[idx] = __float2bfloat16(v);

  // fused next-block projection: p_next[i] = u_next^T v_row
  if (u_next) {
    __syncthreads();
    const uint2 ur = *(const uint2*)(u_next + ch * 4);
    red[0][ch] = v * bflo(ur.x);
    red[1][ch] = v * bfhi(ur.x);
    red[2][ch] = v * bflo(ur.y);
    red[3][ch] = v * bfhi(ur.y);
    __syncthreads();
    float s = red[g][l] + red[g][l + 64] + red[g][l + 128] + red[g][l + 192];
    #pragma unroll
    for (int off = 32; off > 0; off >>= 1) s += __shfl_xor(s, off);
    if (l == 0) p_next[i * 4 + g] = s;
  }
}

extern "C" void kernel_launch(void* const* d_in, const int* in_sizes, int n_in,
                              void* d_out, int out_size, void* d_ws, size_t ws_size,
                              hipStream_t stream)
{
  const bf16* x   = (const bf16*)d_in[0];
  const int*  ei  = (const int*)d_in[1];
  const bf16* W0  = (const bf16*)d_in[2];
  const bf16* u0  = (const bf16*)d_in[3];
  const bf16* c0  = (const bf16*)d_in[4];
  const bf16* b0  = (const bf16*)d_in[5];
  const bf16* sW0 = (const bf16*)d_in[6];
  const bf16* sb0 = (const bf16*)d_in[7];
  const bf16* W1  = (const bf16*)d_in[8];
  const bf16* u1  = (const bf16*)d_in[9];
  const bf16* c1  = (const bf16*)d_in[10];
  const bf16* b1  = (const bf16*)d_in[11];

  const int N = in_sizes[0] / 128;   // 20000
  const int E = in_sizes[1] / 2;     // 320000

  // workspace layout (~58 MB)
  char* ws = (char*)d_ws;
  unsigned char* y = (unsigned char*)ws; ws += (size_t)N * 1024;        // fp8, head-interleaved
  float*  skip0  = (float*)ws;  ws += (size_t)N * 256 * sizeof(float);
  bf16*   h0     = (bf16*)ws;   ws += (size_t)N * 256 * sizeof(bf16);
  float4* p0     = (float4*)ws; ws += (size_t)N * sizeof(float4);
  float4* p1     = (float4*)ws; ws += (size_t)N * sizeof(float4);
  int*    ssrc   = (int*)ws;    ws += (size_t)E * sizeof(int);
  int*    deg    = (int*)ws;    ws += (size_t)N * sizeof(int);
  int*    cursor = (int*)ws;    ws += (size_t)N * sizeof(int);
  int*    rowptr = (int*)ws;    ws += ((size_t)N + 1) * sizeof(int);
  bf16*   Bt0    = (bf16*)ws;   ws += (size_t)1280 * 128 * sizeof(bf16); // [W0|sW0]^T
  bf16*   Bt1    = (bf16*)ws;   ws += (size_t)1024 * 256 * sizeof(bf16); // W1^T

  hipMemsetAsync(deg, 0, 2 * (size_t)N * sizeof(int), stream);  // deg + cursor

  const int eBlocks = (E + 255) / 256;          // 1250
  const int mTiles  = (N + 127) / 128;

  // prep region bases
  const int b4 = 416 + eBlocks;                 // end of hist
  const int b5 = b4 + (2 * E + 255) / 256;      // end of edgecopy
  const int b6 = b5 + (N + 3) / 4;              // end of proj128

  // ---- fused setup: transposes + hist + edgecopy + proj128 ----
  prep_kernel<<<b6, 256, 0, stream>>>(x, ei, W0, sW0, W1, u0, Bt0, Bt1,
                                      deg, (float*)d_out + (size_t)N * 256, p0,
                                      N, E, b4, b5, b6);
  scan_kernel<<<1, 256, 0, stream>>>(deg, rowptr, N);
  scatter_kernel<<<eBlocks, 256, 0, stream>>>(ei, rowptr, cursor, ssrc, E);

  // ---- Block 0 ----
  gemm_mfma_kernel<<<dim3(mTiles, 10), 256, 0, stream>>>(
      x, Bt0, N, 128, y, 1024, skip0, sb0, 256);
  passB_kernel<false, true><<<N, 256, 0, stream>>>(
      rowptr, ssrc, p0, y, c0, b0, skip0, nullptr, nullptr, h0,
      u1, (float*)p1);

  // ---- Block 1 ----
  gemm_mfma_kernel<<<dim3(mTiles, 8), 256, 0, stream>>>(
      h0, Bt1, N, 256, y, 1024, nullptr, nullptr, 256);
  passB_kernel<true, false><<<N, 256, 0, stream>>>(
      rowptr, ssrc, p1, y, c1, b1, nullptr, h0, (float*)d_out, nullptr,
      nullptr, nullptr);
}

// Round 10
// 341.887 us; speedup vs baseline: 1.0917x; 1.0917x over previous
//
#include <hip/hip_runtime.h>
#include <hip/hip_bf16.h>

typedef __hip_bfloat16 bf16;

typedef short bf16x8 __attribute__((ext_vector_type(8)));   // 8 bf16 (4 VGPRs), MFMA A/B frag
typedef float f32x4  __attribute__((ext_vector_type(4)));   // MFMA C/D frag
typedef float f32x2  __attribute__((ext_vector_type(2)));

__device__ __forceinline__ float bflo(unsigned v){ union{unsigned u; float f;} c; c.u = v << 16; return c.f; }
__device__ __forceinline__ float bfhi(unsigned v){ union{unsigned u; float f;} c; c.u = v & 0xffff0000u; return c.f; }

// float -> fp8 e4m3 (OCP on gfx950), single byte
__device__ __forceinline__ unsigned char f32_to_fp8(float v){
  return (unsigned char)(__builtin_amdgcn_cvt_pk_fp8_f32(v, v, 0, false) & 0xFF);
}

// ---------------------------------------------------------------------------
// prep_kernel: horizontal fusion of independent setup work.
//   [0,128)   transpose W0   [128,160) transpose sW0   [160,416) transpose W1
//   [416,b4)  hist           [b4,b5)   edgecopy        [b5,b6)   proj128
// ---------------------------------------------------------------------------
__device__ __forceinline__ void dev_transpose32(
    const bf16* __restrict__ B, bf16* __restrict__ Bt, int K, int NC,
    int bx, int by, int t, bf16 (*tile)[33])
{
  const int tx = t & 31, ty = t >> 5;   // ty 0..7
  #pragma unroll
  for (int i = 0; i < 32; i += 8)
    tile[ty + i][tx] = B[(size_t)(by * 32 + ty + i) * NC + bx * 32 + tx];
  __syncthreads();
  #pragma unroll
  for (int i = 0; i < 32; i += 8)
    Bt[(size_t)(bx * 32 + ty + i) * K + by * 32 + tx] = tile[tx][ty + i];
}

__global__ __launch_bounds__(256) void prep_kernel(
    const bf16* __restrict__ x, const int* __restrict__ ei,
    const bf16* __restrict__ W0, const bf16* __restrict__ sW0,
    const bf16* __restrict__ W1, const bf16* __restrict__ u0,
    bf16* __restrict__ Bt0, bf16* __restrict__ Bt1,
    int* __restrict__ deg, float* __restrict__ eout, float4* __restrict__ p0,
    int N, int E, int b4, int b5, int b6)
{
  __shared__ bf16 tile[32][33];
  const int bid = blockIdx.x;
  const int t   = threadIdx.x;

  if (bid < 128) {
    dev_transpose32(W0, Bt0, 128, 1024, bid & 31, bid >> 5, t, tile);
  } else if (bid < 160) {
    const int lb = bid - 128;
    dev_transpose32(sW0, Bt0 + 1024 * 128, 128, 256, lb & 7, lb >> 3, t, tile);
  } else if (bid < 416) {
    const int lb = bid - 160;
    dev_transpose32(W1, Bt1, 256, 1024, lb & 31, lb >> 5, t, tile);
  } else if (bid < b4) {
    const int e = (bid - 416) * 256 + t;
    if (e < E) atomicAdd(deg + ei[E + e], 1);
  } else if (bid < b5) {
    const int i = (bid - b4) * 256 + t;
    if (i < 2 * E) eout[i] = (float)ei[i];
  } else {                          // proj128: 4 nodes per block
    const int node = (bid - b5) * 4 + (t >> 6);
    if (node >= N) return;
    const int lane = t & 63;
    const unsigned xv = ((const unsigned*)(x + (size_t)node * 128))[lane];
    const float d0 = bflo(xv), d1 = bfhi(xv);
    const uint4 uv = *(const uint4*)(u0 + (size_t)lane * 8);
    float t0 = d0 * bflo(uv.x) + d1 * bflo(uv.z);
    float t1 = d0 * bfhi(uv.x) + d1 * bfhi(uv.z);
    float t2 = d0 * bflo(uv.y) + d1 * bflo(uv.w);
    float t3 = d0 * bfhi(uv.y) + d1 * bfhi(uv.w);
    #pragma unroll
    for (int off = 32; off > 0; off >>= 1) {
      t0 += __shfl_xor(t0, off);
      t1 += __shfl_xor(t1, off);
      t2 += __shfl_xor(t2, off);
      t3 += __shfl_xor(t3, off);
    }
    if (lane == 0) p0[node] = make_float4(t0, t1, t2, t3);
  }
}

// ---------------------------------------------------------------------------
// MFMA GEMM (unchanged from round 8)
// ---------------------------------------------------------------------------
__global__ __launch_bounds__(256) void gemm_mfma_kernel(
    const bf16* __restrict__ A, const bf16* __restrict__ Bt,
    int M, int K,
    unsigned char* __restrict__ Cy, int nsplit,
    float* __restrict__ Cs, const bf16* __restrict__ sbias, int lds_)
{
  constexpr int LDA = 40;
  __shared__ __align__(16) bf16 As[128 * LDA];
  __shared__ __align__(16) bf16 Bs[128 * LDA];

  const int tid  = threadIdx.x;
  const int row0 = blockIdx.x * 128;
  const int col0 = blockIdx.y * 128;
  const int lane = tid & 63;
  const int wave = tid >> 6;
  const int wm   = wave & 1, wn = wave >> 1;
  const int ln   = lane & 15, quad = lane >> 4;

  f32x4 acc[4][4] = {};

  for (int k0 = 0; k0 < K; k0 += 32) {
    #pragma unroll
    for (int rep = 0; rep < 2; ++rep) {
      const int cs = tid + rep * 256;
      const int r  = cs >> 2;
      const int kp = (cs & 3) << 3;
      const int gr = min(row0 + r, M - 1);
      const uint4 va = *(const uint4*)(A  + (size_t)gr * K        + k0 + kp);
      *(uint4*)(As + r * LDA + kp) = va;
      const uint4 vb = *(const uint4*)(Bt + (size_t)(col0 + r) * K + k0 + kp);
      *(uint4*)(Bs + r * LDA + kp) = vb;
    }
    __syncthreads();

    bf16x8 a[4], b[4];
    #pragma unroll
    for (int mi = 0; mi < 4; ++mi)
      a[mi] = *(const bf16x8*)(As + (wm * 64 + mi * 16 + ln) * LDA + quad * 8);
    #pragma unroll
    for (int ni = 0; ni < 4; ++ni)
      b[ni] = *(const bf16x8*)(Bs + (wn * 64 + ni * 16 + ln) * LDA + quad * 8);
    #pragma unroll
    for (int mi = 0; mi < 4; ++mi)
      #pragma unroll
      for (int ni = 0; ni < 4; ++ni)
        acc[mi][ni] = __builtin_amdgcn_mfma_f32_16x16x32_bf16(a[mi], b[ni], acc[mi][ni], 0, 0, 0);
    __syncthreads();
  }

  if (col0 < nsplit) {
    #pragma unroll
    for (int mi = 0; mi < 4; ++mi) {
      const int rbase = row0 + wm * 64 + mi * 16 + quad * 4;
      #pragma unroll
      for (int ni = 0; ni < 4; ++ni) {
        const int col = col0 + wn * 64 + ni * 16 + ln;
        const int ic  = (col & 255) * 4 + (col >> 8);
        #pragma unroll
        for (int r = 0; r < 4; ++r) {
          const int gr = rbase + r;
          if (gr < M) Cy[(size_t)gr * 1024 + ic] = f32_to_fp8(acc[mi][ni][r]);
        }
      }
    }
  } else {
    const int cbase = col0 - nsplit;
    #pragma unroll
    for (int mi = 0; mi < 4; ++mi) {
      const int rbase = row0 + wm * 64 + mi * 16 + quad * 4;
      #pragma unroll
      for (int ni = 0; ni < 4; ++ni) {
        const int col = cbase + wn * 64 + ni * 16 + ln;
        const float bb = __bfloat162float(sbias[col]);
        #pragma unroll
        for (int r = 0; r < 4; ++r) {
          const int gr = rbase + r;
          if (gr < M) Cs[(size_t)gr * lds_ + col] = acc[mi][ni][r] + bb;
        }
      }
    }
  }
}

// ---------------------------------------------------------------------------
// scan; scatter (CSR build) with FUSED passA0: q0 computed bulk-parallel here.
// ---------------------------------------------------------------------------
__global__ __launch_bounds__(256) void scan_kernel(
    const int* __restrict__ deg, int* __restrict__ rowptr, int N)
{
  __shared__ int part[256];
  const int t = threadIdx.x;
  const int chunk = (N + 255) / 256;
  const int start = t * chunk;
  const int stop  = min(start + chunk, N);
  int sum = 0;
  for (int j = start; j < stop; ++j) sum += deg[j];
  part[t] = sum;
  __syncthreads();
  for (int off = 1; off < 256; off <<= 1) {
    int v = (t >= off) ? part[t - off] : 0;
    __syncthreads();
    part[t] += v;
    __syncthreads();
  }
  int base = (t == 0) ? 0 : part[t - 1];
  for (int j = start; j < stop; ++j) { rowptr[j] = base; base += deg[j]; }
  if (t == 255) rowptr[N] = part[255];
}

__global__ __launch_bounds__(256) void scatter_kernel(
    const int* __restrict__ ei, const int* __restrict__ rowptr,
    int* __restrict__ cursor, const float4* __restrict__ p0,
    const bf16* __restrict__ cvec,
    int* __restrict__ ssrc, int* __restrict__ sdst, float4* __restrict__ qs,
    int E)
{
  const int e = (int)((unsigned)blockIdx.x * 256u + threadIdx.x);
  if (e >= E) return;
  const int src = ei[e];
  const int d   = ei[E + e];
  const int pp  = rowptr[d] + atomicAdd(cursor + d, 1);
  ssrc[pp] = src;
  sdst[pp] = d;
  // fused passA0 (bulk-parallel, latency-hidden; NOT inside passB's barriers)
  const float4 ps = p0[src];
  const float4 pd = p0[d];
  const float t0 = ps.x - pd.x + __bfloat162float(cvec[0]);
  const float t1 = ps.y - pd.y + __bfloat162float(cvec[1]);
  const float t2 = ps.z - pd.z + __bfloat162float(cvec[2]);
  const float t3 = ps.w - pd.w + __bfloat162float(cvec[3]);
  const float mx = fmaxf(fmaxf(t0, t1), fmaxf(t2, t3));
  const float e0 = __expf(t0 - mx), e1 = __expf(t1 - mx);
  const float e2 = __expf(t2 - mx), e3 = __expf(t3 - mx);
  const float inv = 1.f / (e0 + e1 + e2 + e3);
  qs[pp] = make_float4(e0 * inv, e1 * inv, e2 * inv, e3 * inv);
}

// passA1: q from p1 over sorted edges (needs p1, so runs after passB0)
__global__ __launch_bounds__(256) void passA_kernel(
    const float4* __restrict__ p, const int* __restrict__ ssrc,
    const int* __restrict__ sdst, const bf16* __restrict__ cvec,
    float4* __restrict__ qs, int E)
{
  const int e = (int)((unsigned)blockIdx.x * 256u + threadIdx.x);
  if (e >= E) return;
  const float4 ps = p[ssrc[e]];
  const float4 pd = p[sdst[e]];
  const float t0 = ps.x - pd.x + __bfloat162float(cvec[0]);
  const float t1 = ps.y - pd.y + __bfloat162float(cvec[1]);
  const float t2 = ps.z - pd.z + __bfloat162float(cvec[2]);
  const float t3 = ps.w - pd.w + __bfloat162float(cvec[3]);
  const float mx = fmaxf(fmaxf(t0, t1), fmaxf(t2, t3));
  const float e0 = __expf(t0 - mx), e1 = __expf(t1 - mx);
  const float e2 = __expf(t2 - mx), e3 = __expf(t3 - mx);
  const float inv = 1.f / (e0 + e1 + e2 + e3);
  qs[e] = make_float4(e0 * inv, e1 * inv, e2 * inv, e3 * inv);
}

// ---------------------------------------------------------------------------
// Pass B (round-8 structure: precomputed qs, simple staging). Lane owns 4
// channels (16B of fp8 head-interleaved y row); 4 waves stride edges,
// unrolled x4 -> 16 row-gathers in flight. PROJ: fused p_next epilogue.
// ---------------------------------------------------------------------------
#define PB_CHUNK 64

template<bool OUT_FLOAT, bool SKIP_FLOAT, bool PROJ>
__global__ __launch_bounds__(256) void passB_kernel(
    const int* __restrict__ rowptr, const int* __restrict__ ssrc,
    const float4* __restrict__ qs, const unsigned char* __restrict__ y,
    const bf16* __restrict__ cvec, const bf16* __restrict__ bias,
    const float* __restrict__ skipf, const bf16* __restrict__ skipb,
    float* __restrict__ outf, bf16* __restrict__ outb,
    const bf16* __restrict__ u_next, float* __restrict__ p_next)
{
  __shared__ int    s_off[PB_CHUNK];
  __shared__ float4 s_q[PB_CHUNK];
  __shared__ float  red[4][256];

  const int i   = blockIdx.x;
  const int t   = threadIdx.x;
  const int g   = t >> 6;
  const int l   = t & 63;
  const int beg = rowptr[i], end = rowptr[i + 1];
  const int deg = end - beg;

  f32x2 ap0 = {0.f, 0.f}, ap1 = {0.f, 0.f}, ap2 = {0.f, 0.f}, ap3 = {0.f, 0.f};

#define PB_BODY(EIDX)                                                          \
  {                                                                            \
    const int    off = s_off[EIDX];                                            \
    const float4 q   = s_q[EIDX];                                              \
    const uint4  v   = *(const uint4*)(y + (size_t)off + l * 16);              \
    f32x2 q01; q01.x = q.x; q01.y = q.y;                                       \
    f32x2 q23; q23.x = q.z; q23.y = q.w;                                       \
    ap0 += q01 * __builtin_amdgcn_cvt_pk_f32_fp8((int)v.x, false)              \
         + q23 * __builtin_amdgcn_cvt_pk_f32_fp8((int)v.x, true);              \
    ap1 += q01 * __builtin_amdgcn_cvt_pk_f32_fp8((int)v.y, false)              \
         + q23 * __builtin_amdgcn_cvt_pk_f32_fp8((int)v.y, true);              \
    ap2 += q01 * __builtin_amdgcn_cvt_pk_f32_fp8((int)v.z, false)              \
         + q23 * __builtin_amdgcn_cvt_pk_f32_fp8((int)v.z, true);              \
    ap3 += q01 * __builtin_amdgcn_cvt_pk_f32_fp8((int)v.w, false)              \
         + q23 * __builtin_amdgcn_cvt_pk_f32_fp8((int)v.w, true);              \
  }

  for (int c0 = 0; c0 < deg; c0 += PB_CHUNK) {
    const int cnt = min(PB_CHUNK, deg - c0);
    __syncthreads();
    if (t < cnt) {
      s_off[t] = ssrc[beg + c0 + t] << 10;
      s_q[t]   = qs[beg + c0 + t];
    }
    __syncthreads();

    int e = g;
    for (; e + 12 < cnt; e += 16) {
      PB_BODY(e) PB_BODY(e + 4) PB_BODY(e + 8) PB_BODY(e + 12)
    }
    for (; e < cnt; e += 4) PB_BODY(e)
  }
#undef PB_BODY

  __syncthreads();
  {
    float4 r;
    r.x = ap0.x + ap0.y; r.y = ap1.x + ap1.y;
    r.z = ap2.x + ap2.y; r.w = ap3.x + ap3.y;
    *(float4*)&red[g][l * 4] = r;
  }
  __syncthreads();

  const int ch = t;
  float acc = red[0][ch] + red[1][ch] + red[2][ch] + red[3][ch];

  const float cc0 = __bfloat162float(cvec[0]), cc1 = __bfloat162float(cvec[1]);
  const float cc2 = __bfloat162float(cvec[2]), cc3 = __bfloat162float(cvec[3]);
  const float mx = fmaxf(fmaxf(cc0, cc1), fmaxf(cc2, cc3));
  const float e0 = __expf(cc0 - mx), e1 = __expf(cc1 - mx);
  const float e2 = __expf(cc2 - mx), e3 = __expf(cc3 - mx);
  const float inv = 1.f / (e0 + e1 + e2 + e3);
  const unsigned vi = *(const unsigned*)(y + (size_t)i * 1024 + ch * 4);
  const f32x2 li  = __builtin_amdgcn_cvt_pk_f32_fp8((int)vi, false);
  const f32x2 hii = __builtin_amdgcn_cvt_pk_f32_fp8((int)vi, true);
  acc += (e0 * li.x + e1 * li.y + e2 * hii.x + e3 * hii.y) * inv;

  const int idx = i * 256 + ch;
  float v = acc / (float)(deg + 1) + __bfloat162float(bias[ch]);
  v += SKIP_FLOAT ? skipf[idx] : __bfloat162float(skipb[idx]);
  v = fmaxf(v, 0.f);
  if (OUT_FLOAT) outf[idx] = v;
  else           outb[idx] = __float2bfloat16(v);

  if constexpr (PROJ) {   // fused next-block projection: p_next[i] = u_next^T v_row
    __syncthreads();
    const uint2 ur = *(const uint2*)(u_next + ch * 4);
    red[0][ch] = v * bflo(ur.x);
    red[1][ch] = v * bfhi(ur.x);
    red[2][ch] = v * bflo(ur.y);
    red[3][ch] = v * bfhi(ur.y);
    __syncthreads();
    float s = red[g][l] + red[g][l + 64] + red[g][l + 128] + red[g][l + 192];
    #pragma unroll
    for (int off = 32; off > 0; off >>= 1) s += __shfl_xor(s, off);
    if (l == 0) p_next[i * 4 + g] = s;
  }
}

extern "C" void kernel_launch(void* const* d_in, const int* in_sizes, int n_in,
                              void* d_out, int out_size, void* d_ws, size_t ws_size,
                              hipStream_t stream)
{
  const bf16* x   = (const bf16*)d_in[0];
  const int*  ei  = (const int*)d_in[1];
  const bf16* W0  = (const bf16*)d_in[2];
  const bf16* u0  = (const bf16*)d_in[3];
  const bf16* c0  = (const bf16*)d_in[4];
  const bf16* b0  = (const bf16*)d_in[5];
  const bf16* sW0 = (const bf16*)d_in[6];
  const bf16* sb0 = (const bf16*)d_in[7];
  const bf16* W1  = (const bf16*)d_in[8];
  const bf16* u1  = (const bf16*)d_in[9];
  const bf16* c1  = (const bf16*)d_in[10];
  const bf16* b1  = (const bf16*)d_in[11];

  const int N = in_sizes[0] / 128;   // 20000
  const int E = in_sizes[1] / 2;     // 320000

  // workspace layout (~65 MB)
  char* ws = (char*)d_ws;
  unsigned char* y = (unsigned char*)ws; ws += (size_t)N * 1024;        // fp8, head-interleaved
  float*  skip0  = (float*)ws;  ws += (size_t)N * 256 * sizeof(float);
  bf16*   h0     = (bf16*)ws;   ws += (size_t)N * 256 * sizeof(bf16);
  float4* qs     = (float4*)ws; ws += (size_t)E * sizeof(float4);
  float4* p0     = (float4*)ws; ws += (size_t)N * sizeof(float4);
  float4* p1     = (float4*)ws; ws += (size_t)N * sizeof(float4);
  int*    ssrc   = (int*)ws;    ws += (size_t)E * sizeof(int);
  int*    sdst   = (int*)ws;    ws += (size_t)E * sizeof(int);
  int*    deg    = (int*)ws;    ws += (size_t)N * sizeof(int);
  int*    cursor = (int*)ws;    ws += (size_t)N * sizeof(int);
  int*    rowptr = (int*)ws;    ws += ((size_t)N + 1) * sizeof(int);
  bf16*   Bt0    = (bf16*)ws;   ws += (size_t)1280 * 128 * sizeof(bf16); // [W0|sW0]^T
  bf16*   Bt1    = (bf16*)ws;   ws += (size_t)1024 * 256 * sizeof(bf16); // W1^T

  hipMemsetAsync(deg, 0, 2 * (size_t)N * sizeof(int), stream);  // deg + cursor

  const int eBlocks = (E + 255) / 256;          // 1250
  const int mTiles  = (N + 127) / 128;

  const int b4 = 416 + eBlocks;
  const int b5 = b4 + (2 * E + 255) / 256;
  const int b6 = b5 + (N + 3) / 4;

  // ---- fused setup: transposes + hist + edgecopy + proj128 ----
  prep_kernel<<<b6, 256, 0, stream>>>(x, ei, W0, sW0, W1, u0, Bt0, Bt1,
                                      deg, (float*)d_out + (size_t)N * 256, p0,
                                      N, E, b4, b5, b6);
  scan_kernel<<<1, 256, 0, stream>>>(deg, rowptr, N);
  scatter_kernel<<<eBlocks, 256, 0, stream>>>(ei, rowptr, cursor, p0, c0,
                                              ssrc, sdst, qs, E);

  // ---- Block 0 ----
  gemm_mfma_kernel<<<dim3(mTiles, 10), 256, 0, stream>>>(
      x, Bt0, N, 128, y, 1024, skip0, sb0, 256);
  passB_kernel<false, true, true><<<N, 256, 0, stream>>>(
      rowptr, ssrc, qs, y, c0, b0, skip0, nullptr, nullptr, h0, u1, (float*)p1);

  // ---- Block 1 ----
  gemm_mfma_kernel<<<dim3(mTiles, 8), 256, 0, stream>>>(
      h0, Bt1, N, 256, y, 1024, nullptr, nullptr, 256);
  passA_kernel<<<eBlocks, 256, 0, stream>>>(p1, ssrc, sdst, c1, qs, E);
  passB_kernel<true, false, false><<<N, 256, 0, stream>>>(
      rowptr, ssrc, qs, y, c1, b1, nullptr, h0, (float*)d_out, nullptr,
      nullptr, nullptr);
}

// Round 11
// 334.339 us; speedup vs baseline: 1.1164x; 1.0226x over previous
//
#include <hip/hip_runtime.h>
#include <hip/hip_bf16.h>

typedef __hip_bfloat16 bf16;

typedef short bf16x8 __attribute__((ext_vector_type(8)));   // 8 bf16 (4 VGPRs), MFMA A/B frag
typedef float f32x4  __attribute__((ext_vector_type(4)));   // MFMA C/D frag
typedef float f32x2  __attribute__((ext_vector_type(2)));

__device__ __forceinline__ float bflo(unsigned v){ union{unsigned u; float f;} c; c.u = v << 16; return c.f; }
__device__ __forceinline__ float bfhi(unsigned v){ union{unsigned u; float f;} c; c.u = v & 0xffff0000u; return c.f; }

// float -> fp8 e4m3 (OCP on gfx950), single byte
__device__ __forceinline__ unsigned char f32_to_fp8(float v){
  return (unsigned char)(__builtin_amdgcn_cvt_pk_fp8_f32(v, v, 0, false) & 0xFF);
}

// ---------------------------------------------------------------------------
// prep_kernel: horizontal fusion of independent setup work.
//   [0,128)   transpose W0   [128,160) transpose sW0   [160,416) transpose W1
//   [416,b4)  hist           [b4,b5)   edgecopy        [b5,b6)   proj128
// ---------------------------------------------------------------------------
__device__ __forceinline__ void dev_transpose32(
    const bf16* __restrict__ B, bf16* __restrict__ Bt, int K, int NC,
    int bx, int by, int t, bf16 (*tile)[33])
{
  const int tx = t & 31, ty = t >> 5;   // ty 0..7
  #pragma unroll
  for (int i = 0; i < 32; i += 8)
    tile[ty + i][tx] = B[(size_t)(by * 32 + ty + i) * NC + bx * 32 + tx];
  __syncthreads();
  #pragma unroll
  for (int i = 0; i < 32; i += 8)
    Bt[(size_t)(bx * 32 + ty + i) * K + by * 32 + tx] = tile[tx][ty + i];
}

__global__ __launch_bounds__(256) void prep_kernel(
    const bf16* __restrict__ x, const int* __restrict__ ei,
    const bf16* __restrict__ W0, const bf16* __restrict__ sW0,
    const bf16* __restrict__ W1, const bf16* __restrict__ u0,
    bf16* __restrict__ Bt0, bf16* __restrict__ Bt1,
    int* __restrict__ deg, float* __restrict__ eout, float4* __restrict__ p0,
    int N, int E, int b4, int b5, int b6)
{
  __shared__ bf16 tile[32][33];
  const int bid = blockIdx.x;
  const int t   = threadIdx.x;

  if (bid < 128) {
    dev_transpose32(W0, Bt0, 128, 1024, bid & 31, bid >> 5, t, tile);
  } else if (bid < 160) {
    const int lb = bid - 128;
    dev_transpose32(sW0, Bt0 + 1024 * 128, 128, 256, lb & 7, lb >> 3, t, tile);
  } else if (bid < 416) {
    const int lb = bid - 160;
    dev_transpose32(W1, Bt1, 256, 1024, lb & 31, lb >> 5, t, tile);
  } else if (bid < b4) {
    const int e = (bid - 416) * 256 + t;
    if (e < E) atomicAdd(deg + ei[E + e], 1);
  } else if (bid < b5) {
    const int i = (bid - b4) * 256 + t;
    if (i < 2 * E) eout[i] = (float)ei[i];
  } else {                          // proj128: 4 nodes per block
    const int node = (bid - b5) * 4 + (t >> 6);
    if (node >= N) return;
    const int lane = t & 63;
    const unsigned xv = ((const unsigned*)(x + (size_t)node * 128))[lane];
    const float d0 = bflo(xv), d1 = bfhi(xv);
    const uint4 uv = *(const uint4*)(u0 + (size_t)lane * 8);
    float t0 = d0 * bflo(uv.x) + d1 * bflo(uv.z);
    float t1 = d0 * bfhi(uv.x) + d1 * bfhi(uv.z);
    float t2 = d0 * bflo(uv.y) + d1 * bflo(uv.w);
    float t3 = d0 * bfhi(uv.y) + d1 * bfhi(uv.w);
    #pragma unroll
    for (int off = 32; off > 0; off >>= 1) {
      t0 += __shfl_xor(t0, off);
      t1 += __shfl_xor(t1, off);
      t2 += __shfl_xor(t2, off);
      t3 += __shfl_xor(t3, off);
    }
    if (lane == 0) p0[node] = make_float4(t0, t1, t2, t3);
  }
}

// ---------------------------------------------------------------------------
// MFMA GEMM (unchanged)
// ---------------------------------------------------------------------------
__global__ __launch_bounds__(256) void gemm_mfma_kernel(
    const bf16* __restrict__ A, const bf16* __restrict__ Bt,
    int M, int K,
    unsigned char* __restrict__ Cy, int nsplit,
    float* __restrict__ Cs, const bf16* __restrict__ sbias, int lds_)
{
  constexpr int LDA = 40;
  __shared__ __align__(16) bf16 As[128 * LDA];
  __shared__ __align__(16) bf16 Bs[128 * LDA];

  const int tid  = threadIdx.x;
  const int row0 = blockIdx.x * 128;
  const int col0 = blockIdx.y * 128;
  const int lane = tid & 63;
  const int wave = tid >> 6;
  const int wm   = wave & 1, wn = wave >> 1;
  const int ln   = lane & 15, quad = lane >> 4;

  f32x4 acc[4][4] = {};

  for (int k0 = 0; k0 < K; k0 += 32) {
    #pragma unroll
    for (int rep = 0; rep < 2; ++rep) {
      const int cs = tid + rep * 256;
      const int r  = cs >> 2;
      const int kp = (cs & 3) << 3;
      const int gr = min(row0 + r, M - 1);
      const uint4 va = *(const uint4*)(A  + (size_t)gr * K        + k0 + kp);
      *(uint4*)(As + r * LDA + kp) = va;
      const uint4 vb = *(const uint4*)(Bt + (size_t)(col0 + r) * K + k0 + kp);
      *(uint4*)(Bs + r * LDA + kp) = vb;
    }
    __syncthreads();

    bf16x8 a[4], b[4];
    #pragma unroll
    for (int mi = 0; mi < 4; ++mi)
      a[mi] = *(const bf16x8*)(As + (wm * 64 + mi * 16 + ln) * LDA + quad * 8);
    #pragma unroll
    for (int ni = 0; ni < 4; ++ni)
      b[ni] = *(const bf16x8*)(Bs + (wn * 64 + ni * 16 + ln) * LDA + quad * 8);
    #pragma unroll
    for (int mi = 0; mi < 4; ++mi)
      #pragma unroll
      for (int ni = 0; ni < 4; ++ni)
        acc[mi][ni] = __builtin_amdgcn_mfma_f32_16x16x32_bf16(a[mi], b[ni], acc[mi][ni], 0, 0, 0);
    __syncthreads();
  }

  if (col0 < nsplit) {
    #pragma unroll
    for (int mi = 0; mi < 4; ++mi) {
      const int rbase = row0 + wm * 64 + mi * 16 + quad * 4;
      #pragma unroll
      for (int ni = 0; ni < 4; ++ni) {
        const int col = col0 + wn * 64 + ni * 16 + ln;
        const int ic  = (col & 255) * 4 + (col >> 8);
        #pragma unroll
        for (int r = 0; r < 4; ++r) {
          const int gr = rbase + r;
          if (gr < M) Cy[(size_t)gr * 1024 + ic] = f32_to_fp8(acc[mi][ni][r]);
        }
      }
    }
  } else {
    const int cbase = col0 - nsplit;
    #pragma unroll
    for (int mi = 0; mi < 4; ++mi) {
      const int rbase = row0 + wm * 64 + mi * 16 + quad * 4;
      #pragma unroll
      for (int ni = 0; ni < 4; ++ni) {
        const int col = cbase + wn * 64 + ni * 16 + ln;
        const float bb = __bfloat162float(sbias[col]);
        #pragma unroll
        for (int r = 0; r < 4; ++r) {
          const int gr = rbase + r;
          if (gr < M) Cs[(size_t)gr * lds_ + col] = acc[mi][ni][r] + bb;
        }
      }
    }
  }
}

// ---------------------------------------------------------------------------
// scan; scatter (CSR build) with fused passA0
// ---------------------------------------------------------------------------
__global__ __launch_bounds__(256) void scan_kernel(
    const int* __restrict__ deg, int* __restrict__ rowptr, int N)
{
  __shared__ int part[256];
  const int t = threadIdx.x;
  const int chunk = (N + 255) / 256;
  const int start = t * chunk;
  const int stop  = min(start + chunk, N);
  int sum = 0;
  for (int j = start; j < stop; ++j) sum += deg[j];
  part[t] = sum;
  __syncthreads();
  for (int off = 1; off < 256; off <<= 1) {
    int v = (t >= off) ? part[t - off] : 0;
    __syncthreads();
    part[t] += v;
    __syncthreads();
  }
  int base = (t == 0) ? 0 : part[t - 1];
  for (int j = start; j < stop; ++j) { rowptr[j] = base; base += deg[j]; }
  if (t == 255) rowptr[N] = part[255];
}

__global__ __launch_bounds__(256) void scatter_kernel(
    const int* __restrict__ ei, const int* __restrict__ rowptr,
    int* __restrict__ cursor, const float4* __restrict__ p0,
    const bf16* __restrict__ cvec,
    int* __restrict__ ssrc, int* __restrict__ sdst, float4* __restrict__ qs,
    int E)
{
  const int e = (int)((unsigned)blockIdx.x * 256u + threadIdx.x);
  if (e >= E) return;
  const int src = ei[e];
  const int d   = ei[E + e];
  const int pp  = rowptr[d] + atomicAdd(cursor + d, 1);
  ssrc[pp] = src;
  sdst[pp] = d;
  const float4 ps = p0[src];
  const float4 pd = p0[d];
  const float t0 = ps.x - pd.x + __bfloat162float(cvec[0]);
  const float t1 = ps.y - pd.y + __bfloat162float(cvec[1]);
  const float t2 = ps.z - pd.z + __bfloat162float(cvec[2]);
  const float t3 = ps.w - pd.w + __bfloat162float(cvec[3]);
  const float mx = fmaxf(fmaxf(t0, t1), fmaxf(t2, t3));
  const float e0 = __expf(t0 - mx), e1 = __expf(t1 - mx);
  const float e2 = __expf(t2 - mx), e3 = __expf(t3 - mx);
  const float inv = 1.f / (e0 + e1 + e2 + e3);
  qs[pp] = make_float4(e0 * inv, e1 * inv, e2 * inv, e3 * inv);
}

// passA1: q from p1 over sorted edges (runs after passB0 produced p1)
__global__ __launch_bounds__(256) void passA_kernel(
    const float4* __restrict__ p, const int* __restrict__ ssrc,
    const int* __restrict__ sdst, const bf16* __restrict__ cvec,
    float4* __restrict__ qs, int E)
{
  const int e = (int)((unsigned)blockIdx.x * 256u + threadIdx.x);
  if (e >= E) return;
  const float4 ps = p[ssrc[e]];
  const float4 pd = p[sdst[e]];
  const float t0 = ps.x - pd.x + __bfloat162float(cvec[0]);
  const float t1 = ps.y - pd.y + __bfloat162float(cvec[1]);
  const float t2 = ps.z - pd.z + __bfloat162float(cvec[2]);
  const float t3 = ps.w - pd.w + __bfloat162float(cvec[3]);
  const float mx = fmaxf(fmaxf(t0, t1), fmaxf(t2, t3));
  const float e0 = __expf(t0 - mx), e1 = __expf(t1 - mx);
  const float e2 = __expf(t2 - mx), e3 = __expf(t3 - mx);
  const float inv = 1.f / (e0 + e1 + e2 + e3);
  qs[e] = make_float4(e0 * inv, e1 * inv, e2 * inv, e3 * inv);
}

// ---------------------------------------------------------------------------
// Pass B v6: ONE WAVE PER NODE (block covers 4 nodes). Lane owns 4 channels
// (16B of the fp8 head-interleaved row) -> one dwordx4 fetches a full 1KB
// y-row per edge. Self-loop = virtual edge with q=softmax(c). Per-wave LDS
// staging slices; barrier count uniform via block-max degree. No cross-wave
// reduction. PROJ epilogue = pure shuffle reduce.
// ---------------------------------------------------------------------------
template<bool OUT_FLOAT, bool SKIP_FLOAT, bool PROJ>
__global__ __launch_bounds__(256) void passB_kernel(
    const int* __restrict__ rowptr, const int* __restrict__ ssrc,
    const float4* __restrict__ qs, const unsigned char* __restrict__ y,
    const bf16* __restrict__ cvec, const bf16* __restrict__ bias,
    const float* __restrict__ skipf, const bf16* __restrict__ skipb,
    float* __restrict__ outf, bf16* __restrict__ outb,
    const bf16* __restrict__ u_next, float4* __restrict__ p_next, int N)
{
  __shared__ int    s_src[4][64];
  __shared__ float4 s_q[4][64];
  __shared__ int    s_deg[4];

  const int t = threadIdx.x;
  const int g = t >> 6;         // wave id -> node
  const int l = t & 63;         // lane -> channels 4l..4l+3
  const int i = blockIdx.x * 4 + g;

  const int beg = (i < N) ? rowptr[i] : 0;
  const int deg = (i < N) ? rowptr[i + 1] - beg : 0;
  if (l == 0) s_deg[g] = deg;

  // self-loop q = softmax(c)
  const float cc0 = __bfloat162float(cvec[0]), cc1 = __bfloat162float(cvec[1]);
  const float cc2 = __bfloat162float(cvec[2]), cc3 = __bfloat162float(cvec[3]);
  const float mx = fmaxf(fmaxf(cc0, cc1), fmaxf(cc2, cc3));
  const float se0 = __expf(cc0 - mx), se1 = __expf(cc1 - mx);
  const float se2 = __expf(cc2 - mx), se3 = __expf(cc3 - mx);
  const float sinv = 1.f / (se0 + se1 + se2 + se3);

  f32x2 ap0 = {0.f, 0.f}, ap1 = {0.f, 0.f}, ap2 = {0.f, 0.f}, ap3 = {0.f, 0.f};

#define PB_BODY_RAW(OFF, QX, QY, QZ, QW)                                       \
  {                                                                            \
    const uint4 v = *(const uint4*)(y + (size_t)(OFF) + l * 16);               \
    f32x2 q01; q01.x = (QX); q01.y = (QY);                                     \
    f32x2 q23; q23.x = (QZ); q23.y = (QW);                                     \
    ap0 += q01 * __builtin_amdgcn_cvt_pk_f32_fp8((int)v.x, false)              \
         + q23 * __builtin_amdgcn_cvt_pk_f32_fp8((int)v.x, true);              \
    ap1 += q01 * __builtin_amdgcn_cvt_pk_f32_fp8((int)v.y, false)              \
         + q23 * __builtin_amdgcn_cvt_pk_f32_fp8((int)v.y, true);              \
    ap2 += q01 * __builtin_amdgcn_cvt_pk_f32_fp8((int)v.z, false)              \
         + q23 * __builtin_amdgcn_cvt_pk_f32_fp8((int)v.z, true);              \
    ap3 += q01 * __builtin_amdgcn_cvt_pk_f32_fp8((int)v.w, false)              \
         + q23 * __builtin_amdgcn_cvt_pk_f32_fp8((int)v.w, true);              \
  }
#define PB_BODY(EIDX)                                                          \
  {                                                                            \
    const int    off_ = s_src[g][EIDX];                                        \
    const float4 q_   = s_q[g][EIDX];                                          \
    PB_BODY_RAW(off_, q_.x, q_.y, q_.z, q_.w)                                  \
  }

  // self-loop as a virtual edge
  if (i < N) PB_BODY_RAW((size_t)i << 10, se0 * sinv, se1 * sinv, se2 * sinv, se3 * sinv)

  __syncthreads();
  const int iters = (max(max(s_deg[0], s_deg[1]), max(s_deg[2], s_deg[3])) + 63) >> 6;

  for (int it = 0; it < iters; ++it) {
    const int c0  = it << 6;
    const int cnt = min(64, deg - c0);   // may be <=0 for short waves
    if (l < cnt) {
      s_src[g][l] = ssrc[beg + c0 + l] << 10;
      s_q[g][l]   = qs[beg + c0 + l];
    }
    __syncthreads();
    int e = 0;
    for (; e + 4 <= cnt; e += 4) { PB_BODY(e) PB_BODY(e + 1) PB_BODY(e + 2) PB_BODY(e + 3) }
    for (; e < cnt; ++e) PB_BODY(e)
    __syncthreads();
  }
#undef PB_BODY
#undef PB_BODY_RAW

  if (i >= N) return;

  float4 r;
  r.x = ap0.x + ap0.y; r.y = ap1.x + ap1.y;
  r.z = ap2.x + ap2.y; r.w = ap3.x + ap3.y;
  const float s = 1.f / (float)(deg + 1);
  const uint2 bb = *(const uint2*)(bias + 4 * l);
  float4 v4;
  v4.x = r.x * s + bflo(bb.x);
  v4.y = r.y * s + bfhi(bb.x);
  v4.z = r.z * s + bflo(bb.y);
  v4.w = r.w * s + bfhi(bb.y);
  const size_t idx = (size_t)i * 256 + 4 * l;
  if (SKIP_FLOAT) {
    const float4 sk = *(const float4*)(skipf + idx);
    v4.x += sk.x; v4.y += sk.y; v4.z += sk.z; v4.w += sk.w;
  } else {
    const uint2 sk = *(const uint2*)(skipb + idx);
    v4.x += bflo(sk.x); v4.y += bfhi(sk.x);
    v4.z += bflo(sk.y); v4.w += bfhi(sk.y);
  }
  v4.x = fmaxf(v4.x, 0.f); v4.y = fmaxf(v4.y, 0.f);
  v4.z = fmaxf(v4.z, 0.f); v4.w = fmaxf(v4.w, 0.f);

  if (OUT_FLOAT) {
    *(float4*)(outf + idx) = v4;
  } else {
    __align__(8) bf16 tmp[4];
    tmp[0] = __float2bfloat16(v4.x); tmp[1] = __float2bfloat16(v4.y);
    tmp[2] = __float2bfloat16(v4.z); tmp[3] = __float2bfloat16(v4.w);
    *(uint2*)(outb + idx) = *(const uint2*)tmp;
  }

  if constexpr (PROJ) {   // p_next[i] = u_next^T v_row, pure shuffle reduce
    const uint4 ua = *(const uint4*)(u_next + l * 16);
    const uint4 ub = *(const uint4*)(u_next + l * 16 + 8);
    float t0 = v4.x*bflo(ua.x) + v4.y*bflo(ua.z) + v4.z*bflo(ub.x) + v4.w*bflo(ub.z);
    float t1 = v4.x*bfhi(ua.x) + v4.y*bfhi(ua.z) + v4.z*bfhi(ub.x) + v4.w*bfhi(ub.z);
    float t2 = v4.x*bflo(ua.y) + v4.y*bflo(ua.w) + v4.z*bflo(ub.y) + v4.w*bflo(ub.w);
    float t3 = v4.x*bfhi(ua.y) + v4.y*bfhi(ua.w) + v4.z*bfhi(ub.y) + v4.w*bfhi(ub.w);
    #pragma unroll
    for (int off = 32; off > 0; off >>= 1) {
      t0 += __shfl_xor(t0, off);
      t1 += __shfl_xor(t1, off);
      t2 += __shfl_xor(t2, off);
      t3 += __shfl_xor(t3, off);
    }
    if (l == 0) p_next[i] = make_float4(t0, t1, t2, t3);
  }
}

extern "C" void kernel_launch(void* const* d_in, const int* in_sizes, int n_in,
                              void* d_out, int out_size, void* d_ws, size_t ws_size,
                              hipStream_t stream)
{
  const bf16* x   = (const bf16*)d_in[0];
  const int*  ei  = (const int*)d_in[1];
  const bf16* W0  = (const bf16*)d_in[2];
  const bf16* u0  = (const bf16*)d_in[3];
  const bf16* c0  = (const bf16*)d_in[4];
  const bf16* b0  = (const bf16*)d_in[5];
  const bf16* sW0 = (const bf16*)d_in[6];
  const bf16* sb0 = (const bf16*)d_in[7];
  const bf16* W1  = (const bf16*)d_in[8];
  const bf16* u1  = (const bf16*)d_in[9];
  const bf16* c1  = (const bf16*)d_in[10];
  const bf16* b1  = (const bf16*)d_in[11];

  const int N = in_sizes[0] / 128;   // 20000
  const int E = in_sizes[1] / 2;     // 320000

  // workspace layout (~65 MB)
  char* ws = (char*)d_ws;
  unsigned char* y = (unsigned char*)ws; ws += (size_t)N * 1024;        // fp8, head-interleaved
  float*  skip0  = (float*)ws;  ws += (size_t)N * 256 * sizeof(float);
  bf16*   h0     = (bf16*)ws;   ws += (size_t)N * 256 * sizeof(bf16);
  float4* qs     = (float4*)ws; ws += (size_t)E * sizeof(float4);
  float4* p0     = (float4*)ws; ws += (size_t)N * sizeof(float4);
  float4* p1     = (float4*)ws; ws += (size_t)N * sizeof(float4);
  int*    ssrc   = (int*)ws;    ws += (size_t)E * sizeof(int);
  int*    sdst   = (int*)ws;    ws += (size_t)E * sizeof(int);
  int*    deg    = (int*)ws;    ws += (size_t)N * sizeof(int);
  int*    cursor = (int*)ws;    ws += (size_t)N * sizeof(int);
  int*    rowptr = (int*)ws;    ws += ((size_t)N + 1) * sizeof(int);
  bf16*   Bt0    = (bf16*)ws;   ws += (size_t)1280 * 128 * sizeof(bf16); // [W0|sW0]^T
  bf16*   Bt1    = (bf16*)ws;   ws += (size_t)1024 * 256 * sizeof(bf16); // W1^T

  hipMemsetAsync(deg, 0, 2 * (size_t)N * sizeof(int), stream);  // deg + cursor

  const int eBlocks  = (E + 255) / 256;          // 1250
  const int mTiles   = (N + 127) / 128;
  const int pbBlocks = (N + 3) / 4;

  const int b4 = 416 + eBlocks;
  const int b5 = b4 + (2 * E + 255) / 256;
  const int b6 = b5 + (N + 3) / 4;

  // ---- fused setup: transposes + hist + edgecopy + proj128 ----
  prep_kernel<<<b6, 256, 0, stream>>>(x, ei, W0, sW0, W1, u0, Bt0, Bt1,
                                      deg, (float*)d_out + (size_t)N * 256, p0,
                                      N, E, b4, b5, b6);
  scan_kernel<<<1, 256, 0, stream>>>(deg, rowptr, N);
  scatter_kernel<<<eBlocks, 256, 0, stream>>>(ei, rowptr, cursor, p0, c0,
                                              ssrc, sdst, qs, E);

  // ---- Block 0 ----
  gemm_mfma_kernel<<<dim3(mTiles, 10), 256, 0, stream>>>(
      x, Bt0, N, 128, y, 1024, skip0, sb0, 256);
  passB_kernel<false, true, true><<<pbBlocks, 256, 0, stream>>>(
      rowptr, ssrc, qs, y, c0, b0, skip0, nullptr, nullptr, h0, u1, p1, N);

  // ---- Block 1 ----
  gemm_mfma_kernel<<<dim3(mTiles, 8), 256, 0, stream>>>(
      h0, Bt1, N, 256, y, 1024, nullptr, nullptr, 256);
  passA_kernel<<<eBlocks, 256, 0, stream>>>(p1, ssrc, sdst, c1, qs, E);
  passB_kernel<true, false, false><<<pbBlocks, 256, 0, stream>>>(
      rowptr, ssrc, qs, y, c1, b1, nullptr, h0, (float*)d_out, nullptr,
      nullptr, nullptr, N);
}

// Round 12
// 300.127 us; speedup vs baseline: 1.2436x; 1.1140x over previous
//
#include <hip/hip_runtime.h>
#include <hip/hip_bf16.h>

typedef __hip_bfloat16 bf16;

typedef short bf16x8 __attribute__((ext_vector_type(8)));   // 8 bf16 (4 VGPRs), MFMA A/B frag
typedef float f32x4  __attribute__((ext_vector_type(4)));   // MFMA C/D frag

__device__ __forceinline__ float bflo(unsigned v){ union{unsigned u; float f;} c; c.u = v << 16; return c.f; }
__device__ __forceinline__ float bfhi(unsigned v){ union{unsigned u; float f;} c; c.u = v & 0xffff0000u; return c.f; }
__device__ __forceinline__ unsigned short f2bf(float v){
  union{float f; unsigned u;} c; c.f = v;
  unsigned r = (c.u + 0x7fff + ((c.u >> 16) & 1)) >> 16;   // RNE
  return (unsigned short)r;
}

// ---------------------------------------------------------------------------
// prep_kernel: fused setup.
//   [0,128)   W0  -> Btc0 rows (head-permuted): Btc0[c&255][ (c>>8)*128 + k ]
//   [128,160) sW0 -> Btc0[c][512 + k]
//   [160,416) W1  -> Bt1 [c&255][ (c>>8)*256 + k ]
//   [416,b4)  hist   [b4,b5) edgecopy   [b5,b6) proj128 (p0)
// ---------------------------------------------------------------------------
__device__ __forceinline__ void dev_t32(
    const bf16* __restrict__ B, int ldB, int sr, int sc,
    bf16* __restrict__ Bt, int ldBt, int dr, int dc,
    int t, bf16 (*tile)[33])
{
  const int tx = t & 31, ty = t >> 5;   // ty 0..7
  #pragma unroll
  for (int i = 0; i < 32; i += 8)
    tile[ty + i][tx] = B[(size_t)(sr + ty + i) * ldB + sc + tx];
  __syncthreads();
  #pragma unroll
  for (int i = 0; i < 32; i += 8)
    Bt[(size_t)(dr + ty + i) * ldBt + dc + tx] = tile[tx][ty + i];
}

__global__ __launch_bounds__(256) void prep_kernel(
    const bf16* __restrict__ x, const int* __restrict__ ei,
    const bf16* __restrict__ W0, const bf16* __restrict__ sW0,
    const bf16* __restrict__ W1, const bf16* __restrict__ u0,
    bf16* __restrict__ Btc0, bf16* __restrict__ Bt1,
    int* __restrict__ deg, float* __restrict__ eout, float4* __restrict__ p0,
    int N, int E, int b4, int b5)
{
  __shared__ bf16 tile[32][33];
  const int bid = blockIdx.x;
  const int t   = threadIdx.x;

  if (bid < 128) {                       // W0 [128][1024]: bx=bid&31, by=bid>>5
    const int bx = bid & 31, by = bid >> 5;
    dev_t32(W0, 1024, by * 32, bx * 32,
            Btc0, 640, (bx & 7) * 32, (bx >> 3) * 128 + by * 32, t, tile);
  } else if (bid < 160) {                // sW0 [128][256]: bx=lb&7, by=lb>>3
    const int lb = bid - 128, bx = lb & 7, by = lb >> 3;
    dev_t32(sW0, 256, by * 32, bx * 32,
            Btc0, 640, bx * 32, 512 + by * 32, t, tile);
  } else if (bid < 416) {                // W1 [256][1024]: bx=lb&31, by=lb>>5
    const int lb = bid - 160, bx = lb & 31, by = lb >> 5;
    dev_t32(W1, 1024, by * 32, bx * 32,
            Bt1, 1024, (bx & 7) * 32, (bx >> 3) * 256 + by * 32, t, tile);
  } else if (bid < b4) {
    const int e = (bid - 416) * 256 + t;
    if (e < E) atomicAdd(deg + ei[E + e], 1);
  } else if (bid < b5) {
    const int i = (bid - b4) * 256 + t;
    if (i < 2 * E) eout[i] = (float)ei[i];
  } else {                               // proj128: 4 nodes/block
    const int node = (bid - b5) * 4 + (t >> 6);
    if (node >= N) return;
    const int lane = t & 63;
    const unsigned xv = ((const unsigned*)(x + (size_t)node * 128))[lane];
    const float d0 = bflo(xv), d1 = bfhi(xv);
    const uint4 uv = *(const uint4*)(u0 + (size_t)lane * 8);
    float t0 = d0 * bflo(uv.x) + d1 * bflo(uv.z);
    float t1 = d0 * bfhi(uv.x) + d1 * bfhi(uv.z);
    float t2 = d0 * bflo(uv.y) + d1 * bflo(uv.w);
    float t3 = d0 * bfhi(uv.y) + d1 * bfhi(uv.w);
    #pragma unroll
    for (int off = 32; off > 0; off >>= 1) {
      t0 += __shfl_xor(t0, off);
      t1 += __shfl_xor(t1, off);
      t2 += __shfl_xor(t2, off);
      t3 += __shfl_xor(t3, off);
    }
    if (lane == 0) p0[node] = make_float4(t0, t1, t2, t3);
  }
}

// ---------------------------------------------------------------------------
// gemm_cat: C[M x 256] = [A1 | A2][M x (K1+K2)] @ Bt[256 x (K1+K2)] (n-major)
// 128x128 tile, 4 waves 2x2, 16x16x32 MFMA, BK=32. K1%32==0.
// MODE 0: v = acc + b0[col] + sb0[col]; relu; store bf16 -> h0
// MODE 1: v = acc + b1[col] + bf16(h0[gr][col]); relu; store f32 -> out
// ---------------------------------------------------------------------------
template<int MODE>
__global__ __launch_bounds__(256) void gemm_cat_kernel(
    const bf16* __restrict__ A1, int K1, const bf16* __restrict__ A2, int K2,
    const bf16* __restrict__ Bt, int ldBt, int M,
    const bf16* __restrict__ bias1, const bf16* __restrict__ bias2,
    const bf16* __restrict__ hadd, bf16* __restrict__ outb,
    float* __restrict__ outf)
{
  constexpr int LDA = 40;
  __shared__ __align__(16) bf16 As[128 * LDA];
  __shared__ __align__(16) bf16 Bs[128 * LDA];

  const int tid  = threadIdx.x;
  const int row0 = blockIdx.x * 128;
  const int col0 = blockIdx.y * 128;
  const int lane = tid & 63;
  const int wave = tid >> 6;
  const int wm   = wave & 1, wn = wave >> 1;
  const int ln   = lane & 15, quad = lane >> 4;
  const int K    = K1 + K2;

  f32x4 acc[4][4] = {};

  for (int k0 = 0; k0 < K; k0 += 32) {
    #pragma unroll
    for (int rep = 0; rep < 2; ++rep) {
      const int cs = tid + rep * 256;
      const int r  = cs >> 2;
      const int kp = (cs & 3) << 3;
      const int gr = min(row0 + r, M - 1);
      uint4 va;
      if (k0 < K1) va = *(const uint4*)(A1 + (size_t)gr * K1 + k0 + kp);
      else         va = *(const uint4*)(A2 + (size_t)gr * K2 + (k0 - K1) + kp);
      *(uint4*)(As + r * LDA + kp) = va;
      const uint4 vb = *(const uint4*)(Bt + (size_t)(col0 + r) * ldBt + k0 + kp);
      *(uint4*)(Bs + r * LDA + kp) = vb;
    }
    __syncthreads();

    bf16x8 a[4], b[4];
    #pragma unroll
    for (int mi = 0; mi < 4; ++mi)
      a[mi] = *(const bf16x8*)(As + (wm * 64 + mi * 16 + ln) * LDA + quad * 8);
    #pragma unroll
    for (int ni = 0; ni < 4; ++ni)
      b[ni] = *(const bf16x8*)(Bs + (wn * 64 + ni * 16 + ln) * LDA + quad * 8);
    #pragma unroll
    for (int mi = 0; mi < 4; ++mi)
      #pragma unroll
      for (int ni = 0; ni < 4; ++ni)
        acc[mi][ni] = __builtin_amdgcn_mfma_f32_16x16x32_bf16(a[mi], b[ni], acc[mi][ni], 0, 0, 0);
    __syncthreads();
  }

  #pragma unroll
  for (int mi = 0; mi < 4; ++mi) {
    const int rbase = row0 + wm * 64 + mi * 16 + quad * 4;
    #pragma unroll
    for (int ni = 0; ni < 4; ++ni) {
      const int col = col0 + wn * 64 + ni * 16 + ln;
      float bb = __bfloat162float(bias1[col]);
      if (MODE == 0) bb += __bfloat162float(bias2[col]);
      #pragma unroll
      for (int r = 0; r < 4; ++r) {
        const int gr = rbase + r;
        if (gr >= M) continue;
        const size_t idx = (size_t)gr * 256 + col;
        float v = acc[mi][ni][r] + bb;
        if (MODE == 1) v += __bfloat162float(hadd[idx]);
        v = fmaxf(v, 0.f);
        if (MODE == 0) outb[idx] = __float2bfloat16(v);
        else           outf[idx] = v;
      }
    }
  }
}

// ---------------------------------------------------------------------------
// scan; scatter (CSR build) + fused passA0
// ---------------------------------------------------------------------------
__global__ __launch_bounds__(256) void scan_kernel(
    const int* __restrict__ deg, int* __restrict__ rowptr, int N)
{
  __shared__ int part[256];
  const int t = threadIdx.x;
  const int chunk = (N + 255) / 256;
  const int start = t * chunk;
  const int stop  = min(start + chunk, N);
  int sum = 0;
  for (int j = start; j < stop; ++j) sum += deg[j];
  part[t] = sum;
  __syncthreads();
  for (int off = 1; off < 256; off <<= 1) {
    int v = (t >= off) ? part[t - off] : 0;
    __syncthreads();
    part[t] += v;
    __syncthreads();
  }
  int base = (t == 0) ? 0 : part[t - 1];
  for (int j = start; j < stop; ++j) { rowptr[j] = base; base += deg[j]; }
  if (t == 255) rowptr[N] = part[255];
}

__global__ __launch_bounds__(256) void scatter_kernel(
    const int* __restrict__ ei, const int* __restrict__ rowptr,
    int* __restrict__ cursor, const float4* __restrict__ p0,
    const bf16* __restrict__ cvec,
    int* __restrict__ ssrc, int* __restrict__ sdst, float4* __restrict__ qs,
    int E)
{
  const int e = (int)((unsigned)blockIdx.x * 256u + threadIdx.x);
  if (e >= E) return;
  const int src = ei[e];
  const int d   = ei[E + e];
  const int pp  = rowptr[d] + atomicAdd(cursor + d, 1);
  ssrc[pp] = src;
  sdst[pp] = d;
  const float4 ps = p0[src];
  const float4 pd = p0[d];
  const float t0 = ps.x - pd.x + __bfloat162float(cvec[0]);
  const float t1 = ps.y - pd.y + __bfloat162float(cvec[1]);
  const float t2 = ps.z - pd.z + __bfloat162float(cvec[2]);
  const float t3 = ps.w - pd.w + __bfloat162float(cvec[3]);
  const float mx = fmaxf(fmaxf(t0, t1), fmaxf(t2, t3));
  const float e0 = __expf(t0 - mx), e1 = __expf(t1 - mx);
  const float e2 = __expf(t2 - mx), e3 = __expf(t3 - mx);
  const float inv = 1.f / (e0 + e1 + e2 + e3);
  qs[pp] = make_float4(e0 * inv, e1 * inv, e2 * inv, e3 * inv);
}

// passA1: q from p1 over sorted edges
__global__ __launch_bounds__(256) void passA_kernel(
    const float4* __restrict__ p, const int* __restrict__ ssrc,
    const int* __restrict__ sdst, const bf16* __restrict__ cvec,
    float4* __restrict__ qs, int E)
{
  const int e = (int)((unsigned)blockIdx.x * 256u + threadIdx.x);
  if (e >= E) return;
  const float4 ps = p[ssrc[e]];
  const float4 pd = p[sdst[e]];
  const float t0 = ps.x - pd.x + __bfloat162float(cvec[0]);
  const float t1 = ps.y - pd.y + __bfloat162float(cvec[1]);
  const float t2 = ps.z - pd.z + __bfloat162float(cvec[2]);
  const float t3 = ps.w - pd.w + __bfloat162float(cvec[3]);
  const float mx = fmaxf(fmaxf(t0, t1), fmaxf(t2, t3));
  const float e0 = __expf(t0 - mx), e1 = __expf(t1 - mx);
  const float e2 = __expf(t2 - mx), e3 = __expf(t3 - mx);
  const float inv = 1.f / (e0 + e1 + e2 + e3);
  qs[e] = make_float4(e0 * inv, e1 * inv, e2 * inv, e3 * inv);
}

// proj256: p1[i] = u1^T h0[i], one wave per node
__global__ __launch_bounds__(256) void proj256_kernel(
    const bf16* __restrict__ h, const bf16* __restrict__ u,
    float4* __restrict__ p, int N)
{
  const int node = (int)(((unsigned)blockIdx.x * 256u + threadIdx.x) >> 6);
  if (node >= N) return;
  const int lane = threadIdx.x & 63;
  const uint2 hv = *(const uint2*)(h + (size_t)node * 256 + lane * 4);
  const float d0 = bflo(hv.x), d1 = bfhi(hv.x);
  const float d2 = bflo(hv.y), d3 = bfhi(hv.y);
  const uint4 ua = *(const uint4*)(u + (size_t)lane * 16);
  const uint4 ub = *(const uint4*)(u + (size_t)lane * 16 + 8);
  float t0 = d0*bflo(ua.x) + d1*bflo(ua.z) + d2*bflo(ub.x) + d3*bflo(ub.z);
  float t1 = d0*bfhi(ua.x) + d1*bfhi(ua.z) + d2*bfhi(ub.x) + d3*bfhi(ub.z);
  float t2 = d0*bflo(ua.y) + d1*bflo(ua.w) + d2*bflo(ub.y) + d3*bflo(ub.w);
  float t3 = d0*bfhi(ua.y) + d1*bfhi(ua.w) + d2*bfhi(ub.y) + d3*bfhi(ub.w);
  #pragma unroll
  for (int off = 32; off > 0; off >>= 1) {
    t0 += __shfl_xor(t0, off);
    t1 += __shfl_xor(t1, off);
    t2 += __shfl_xor(t2, off);
    t3 += __shfl_xor(t3, off);
  }
  if (lane == 0) p[node] = make_float4(t0, t1, t2, t3);
}

// ---------------------------------------------------------------------------
// passF<CIN>: F[i][h*CIN + ch] = (1/(deg+1)) * sum_e q_eh * feat[src][ch]
// (self-loop included with q = softmax(c)). One wave per node, 4 nodes/block.
// CIN=128: lane owns ch {2l,2l+1}; CIN=256: ch {4l..4l+3}.
// ---------------------------------------------------------------------------
template<int CIN>
__global__ __launch_bounds__(256) void passF_kernel(
    const int* __restrict__ rowptr, const int* __restrict__ ssrc,
    const float4* __restrict__ qs, const bf16* __restrict__ feat,
    const bf16* __restrict__ cvec, bf16* __restrict__ F, int N)
{
  __shared__ int    s_src[4][64];
  __shared__ float4 s_q[4][64];
  __shared__ int    s_deg[4];

  const int t = threadIdx.x;
  const int g = t >> 6;
  const int l = t & 63;
  const int i = blockIdx.x * 4 + g;

  const int beg = (i < N) ? rowptr[i] : 0;
  const int deg = (i < N) ? rowptr[i + 1] - beg : 0;
  if (l == 0) s_deg[g] = deg;

  const float cc0 = __bfloat162float(cvec[0]), cc1 = __bfloat162float(cvec[1]);
  const float cc2 = __bfloat162float(cvec[2]), cc3 = __bfloat162float(cvec[3]);
  const float mx = fmaxf(fmaxf(cc0, cc1), fmaxf(cc2, cc3));
  const float se0 = __expf(cc0 - mx), se1 = __expf(cc1 - mx);
  const float se2 = __expf(cc2 - mx), se3 = __expf(cc3 - mx);
  const float sinv = 1.f / (se0 + se1 + se2 + se3);

  constexpr int CPL = (CIN == 128) ? 2 : 4;   // channels per lane
  float f[4][CPL];
  #pragma unroll
  for (int h = 0; h < 4; ++h)
    #pragma unroll
    for (int c = 0; c < CPL; ++c) f[h][c] = 0.f;

#define PF_BODY(SRC, QX, QY, QZ, QW)                                           \
  {                                                                            \
    if (CIN == 128) {                                                          \
      const unsigned v = *(const unsigned*)(feat + (size_t)(SRC) * 128 + l*2); \
      const float d0 = bflo(v), d1 = bfhi(v);                                  \
      f[0][0] += (QX) * d0; f[0][1] += (QX) * d1;                              \
      f[1][0] += (QY) * d0; f[1][1] += (QY) * d1;                              \
      f[2][0] += (QZ) * d0; f[2][1] += (QZ) * d1;                              \
      f[3][0] += (QW) * d0; f[3][1] += (QW) * d1;                              \
    } else {                                                                   \
      const uint2 v = *(const uint2*)(feat + (size_t)(SRC) * 256 + l*4);       \
      const float d0 = bflo(v.x), d1 = bfhi(v.x);                              \
      const float d2 = bflo(v.y), d3 = bfhi(v.y);                              \
      f[0][0] += (QX)*d0; f[0][1] += (QX)*d1; f[0][2] += (QX)*d2; f[0][3] += (QX)*d3; \
      f[1][0] += (QY)*d0; f[1][1] += (QY)*d1; f[1][2] += (QY)*d2; f[1][3] += (QY)*d3; \
      f[2][0] += (QZ)*d0; f[2][1] += (QZ)*d1; f[2][2] += (QZ)*d2; f[2][3] += (QZ)*d3; \
      f[3][0] += (QW)*d0; f[3][1] += (QW)*d1; f[3][2] += (QW)*d2; f[3][3] += (QW)*d3; \
    }                                                                          \
  }
#define PF_EDGE(EIDX)                                                          \
  {                                                                            \
    const int    src_ = s_src[g][EIDX];                                        \
    const float4 q_   = s_q[g][EIDX];                                          \
    PF_BODY(src_, q_.x, q_.y, q_.z, q_.w)                                      \
  }

  if (i < N) PF_BODY(i, se0 * sinv, se1 * sinv, se2 * sinv, se3 * sinv)

  __syncthreads();
  const int iters = (max(max(s_deg[0], s_deg[1]), max(s_deg[2], s_deg[3])) + 63) >> 6;

  for (int it = 0; it < iters; ++it) {
    const int c0  = it << 6;
    const int cnt = min(64, deg - c0);
    if (l < cnt) {
      s_src[g][l] = ssrc[beg + c0 + l];
      s_q[g][l]   = qs[beg + c0 + l];
    }
    __syncthreads();
    int e = 0;
    for (; e + 4 <= cnt; e += 4) { PF_EDGE(e) PF_EDGE(e + 1) PF_EDGE(e + 2) PF_EDGE(e + 3) }
    for (; e < cnt; ++e) PF_EDGE(e)
    __syncthreads();
  }
#undef PF_EDGE
#undef PF_BODY

  if (i >= N) return;
  const float s = 1.f / (float)(deg + 1);
  if (CIN == 128) {
    #pragma unroll
    for (int h = 0; h < 4; ++h) {
      const unsigned pk = (unsigned)f2bf(f[h][0] * s) | ((unsigned)f2bf(f[h][1] * s) << 16);
      *(unsigned*)(F + (size_t)i * 512 + h * 128 + 2 * l) = pk;
    }
  } else {
    #pragma unroll
    for (int h = 0; h < 4; ++h) {
      uint2 pk;
      pk.x = (unsigned)f2bf(f[h][0] * s) | ((unsigned)f2bf(f[h][1] * s) << 16);
      pk.y = (unsigned)f2bf(f[h][2] * s) | ((unsigned)f2bf(f[h][3] * s) << 16);
      *(uint2*)(F + (size_t)i * 1024 + h * 256 + 4 * l) = pk;
    }
  }
}

extern "C" void kernel_launch(void* const* d_in, const int* in_sizes, int n_in,
                              void* d_out, int out_size, void* d_ws, size_t ws_size,
                              hipStream_t stream)
{
  const bf16* x   = (const bf16*)d_in[0];
  const int*  ei  = (const int*)d_in[1];
  const bf16* W0  = (const bf16*)d_in[2];
  const bf16* u0  = (const bf16*)d_in[3];
  const bf16* c0  = (const bf16*)d_in[4];
  const bf16* b0  = (const bf16*)d_in[5];
  const bf16* sW0 = (const bf16*)d_in[6];
  const bf16* sb0 = (const bf16*)d_in[7];
  const bf16* W1  = (const bf16*)d_in[8];
  const bf16* u1  = (const bf16*)d_in[9];
  const bf16* c1  = (const bf16*)d_in[10];
  const bf16* b1  = (const bf16*)d_in[11];

  const int N = in_sizes[0] / 128;   // 20000
  const int E = in_sizes[1] / 2;     // 320000

  // workspace (~62 MB)
  char* ws = (char*)d_ws;
  bf16*   F      = (bf16*)ws;   ws += (size_t)N * 1024 * sizeof(bf16);  // F0 [N][512] then F1 [N][1024]
  bf16*   h0     = (bf16*)ws;   ws += (size_t)N * 256 * sizeof(bf16);
  float4* qs     = (float4*)ws; ws += (size_t)E * sizeof(float4);
  float4* p0     = (float4*)ws; ws += (size_t)N * sizeof(float4);
  float4* p1     = (float4*)ws; ws += (size_t)N * sizeof(float4);
  int*    ssrc   = (int*)ws;    ws += (size_t)E * sizeof(int);
  int*    sdst   = (int*)ws;    ws += (size_t)E * sizeof(int);
  int*    deg    = (int*)ws;    ws += (size_t)N * sizeof(int);
  int*    cursor = (int*)ws;    ws += (size_t)N * sizeof(int);
  int*    rowptr = (int*)ws;    ws += ((size_t)N + 1) * sizeof(int);
  bf16*   Btc0   = (bf16*)ws;   ws += (size_t)256 * 640 * sizeof(bf16);  // [stack_h W0 | sW0]^T
  bf16*   Bt1    = (bf16*)ws;   ws += (size_t)256 * 1024 * sizeof(bf16); // stack_h W1 ^T

  hipMemsetAsync(deg, 0, 2 * (size_t)N * sizeof(int), stream);  // deg + cursor

  const int eBlocks  = (E + 255) / 256;          // 1250
  const int mTiles   = (N + 127) / 128;          // 157
  const int nwBlocks = (N + 3) / 4;              // wave-per-node kernels

  const int b4 = 416 + eBlocks;
  const int b5 = b4 + (2 * E + 255) / 256;
  const int b6 = b5 + nwBlocks;

  // ---- setup: weight reshuffles + hist + edgecopy + proj128 ----
  prep_kernel<<<b6, 256, 0, stream>>>(x, ei, W0, sW0, W1, u0, Btc0, Bt1,
                                      deg, (float*)d_out + (size_t)N * 256, p0,
                                      N, E, b4, b5);
  scan_kernel<<<1, 256, 0, stream>>>(deg, rowptr, N);
  scatter_kernel<<<eBlocks, 256, 0, stream>>>(ei, rowptr, cursor, p0, c0,
                                              ssrc, sdst, qs, E);

  // ---- Block 0: F0 = scaled scatter of x; h0 = relu([F0|x]@Btc0 + b0+sb0) ----
  passF_kernel<128><<<nwBlocks, 256, 0, stream>>>(rowptr, ssrc, qs, x, c0, F, N);
  gemm_cat_kernel<0><<<dim3(mTiles, 2), 256, 0, stream>>>(
      F, 512, x, 128, Btc0, 640, N, b0, sb0, nullptr, h0, nullptr);

  // ---- Block 1: p1; q1; F1 = scaled scatter of h0; out = relu(F1@Bt1 + b1 + h0) ----
  proj256_kernel<<<nwBlocks, 256, 0, stream>>>(h0, u1, p1, N);
  passA_kernel<<<eBlocks, 256, 0, stream>>>(p1, ssrc, sdst, c1, qs, E);
  passF_kernel<256><<<nwBlocks, 256, 0, stream>>>(rowptr, ssrc, qs, h0, c1, F, N);
  gemm_cat_kernel<1><<<dim3(mTiles, 2), 256, 0, stream>>>(
      F, 1024, nullptr, 0, Bt1, 1024, N, b1, nullptr, h0, nullptr, (float*)d_out);
}

// Round 13
// 291.917 us; speedup vs baseline: 1.2786x; 1.0281x over previous
//
#include <hip/hip_runtime.h>
#include <hip/hip_bf16.h>

typedef __hip_bfloat16 bf16;

typedef short bf16x8 __attribute__((ext_vector_type(8)));   // 8 bf16 (4 VGPRs), MFMA A/B frag
typedef float f32x4  __attribute__((ext_vector_type(4)));   // MFMA C/D frag

__device__ __forceinline__ float bflo(unsigned v){ union{unsigned u; float f;} c; c.u = v << 16; return c.f; }
__device__ __forceinline__ float bfhi(unsigned v){ union{unsigned u; float f;} c; c.u = v & 0xffff0000u; return c.f; }
__device__ __forceinline__ unsigned short f2bf(float v){
  union{float f; unsigned u;} c; c.f = v;
  unsigned r = (c.u + 0x7fff + ((c.u >> 16) & 1)) >> 16;   // RNE
  return (unsigned short)r;
}

// ---------------------------------------------------------------------------
// prep_kernel: fused setup.
//   [0,128)   W0  -> Btc0 rows (head-permuted): Btc0[c&255][ (c>>8)*128 + k ]
//   [128,160) sW0 -> Btc0[c][512 + k]
//   [160,416) W1  -> Bt1 [c&255][ (c>>8)*256 + k ]
//   [416,b4)  hist   [b4,b5) edgecopy   [b5,b6) proj128 (p0)
// ---------------------------------------------------------------------------
__device__ __forceinline__ void dev_t32(
    const bf16* __restrict__ B, int ldB, int sr, int sc,
    bf16* __restrict__ Bt, int ldBt, int dr, int dc,
    int t, bf16 (*tile)[33])
{
  const int tx = t & 31, ty = t >> 5;   // ty 0..7
  #pragma unroll
  for (int i = 0; i < 32; i += 8)
    tile[ty + i][tx] = B[(size_t)(sr + ty + i) * ldB + sc + tx];
  __syncthreads();
  #pragma unroll
  for (int i = 0; i < 32; i += 8)
    Bt[(size_t)(dr + ty + i) * ldBt + dc + tx] = tile[tx][ty + i];
}

__global__ __launch_bounds__(256) void prep_kernel(
    const bf16* __restrict__ x, const int* __restrict__ ei,
    const bf16* __restrict__ W0, const bf16* __restrict__ sW0,
    const bf16* __restrict__ W1, const bf16* __restrict__ u0,
    bf16* __restrict__ Btc0, bf16* __restrict__ Bt1,
    int* __restrict__ deg, float* __restrict__ eout, float4* __restrict__ p0,
    int N, int E, int b4, int b5)
{
  __shared__ bf16 tile[32][33];
  const int bid = blockIdx.x;
  const int t   = threadIdx.x;

  if (bid < 128) {                       // W0 [128][1024]
    const int bx = bid & 31, by = bid >> 5;
    dev_t32(W0, 1024, by * 32, bx * 32,
            Btc0, 640, (bx & 7) * 32, (bx >> 3) * 128 + by * 32, t, tile);
  } else if (bid < 160) {                // sW0 [128][256]
    const int lb = bid - 128, bx = lb & 7, by = lb >> 3;
    dev_t32(sW0, 256, by * 32, bx * 32,
            Btc0, 640, bx * 32, 512 + by * 32, t, tile);
  } else if (bid < 416) {                // W1 [256][1024]
    const int lb = bid - 160, bx = lb & 31, by = lb >> 5;
    dev_t32(W1, 1024, by * 32, bx * 32,
            Bt1, 1024, (bx & 7) * 32, (bx >> 3) * 256 + by * 32, t, tile);
  } else if (bid < b4) {
    const int e = (bid - 416) * 256 + t;
    if (e < E) atomicAdd(deg + ei[E + e], 1);
  } else if (bid < b5) {
    const int i = (bid - b4) * 256 + t;
    if (i < 2 * E) eout[i] = (float)ei[i];
  } else {                               // proj128: 4 nodes/block
    const int node = (bid - b5) * 4 + (t >> 6);
    if (node >= N) return;
    const int lane = t & 63;
    const unsigned xv = ((const unsigned*)(x + (size_t)node * 128))[lane];
    const float d0 = bflo(xv), d1 = bfhi(xv);
    const uint4 uv = *(const uint4*)(u0 + (size_t)lane * 8);
    float t0 = d0 * bflo(uv.x) + d1 * bflo(uv.z);
    float t1 = d0 * bfhi(uv.x) + d1 * bfhi(uv.z);
    float t2 = d0 * bflo(uv.y) + d1 * bflo(uv.w);
    float t3 = d0 * bfhi(uv.y) + d1 * bfhi(uv.w);
    #pragma unroll
    for (int off = 32; off > 0; off >>= 1) {
      t0 += __shfl_xor(t0, off);
      t1 += __shfl_xor(t1, off);
      t2 += __shfl_xor(t2, off);
      t3 += __shfl_xor(t3, off);
    }
    if (lane == 0) p0[node] = make_float4(t0, t1, t2, t3);
  }
}

// ---------------------------------------------------------------------------
// gemm_cat v2: C[M x 256] = [A1 | A2][M x (K1+K2)] @ Bt[256 x (K1+K2)]
// BM=64, BN=128, BK=32 -> grid (2, M/64) = 626 blocks (fixes 11% occupancy
// of the 128x128 tile at N=256: only 314 blocks => ~1.2 blk/CU, no latency
// overlap). 4 waves: wave = 32 rows x 64 cols = 2x4 MFMA tiles, acc[2][4].
// MODE 0: v = acc + b0[col] + sb0[col]; relu; store bf16 -> h0
// MODE 1: v = acc + b1[col] + bf16(h0[gr][col]); relu; store f32 -> out
// ---------------------------------------------------------------------------
template<int MODE>
__global__ __launch_bounds__(256) void gemm_cat_kernel(
    const bf16* __restrict__ A1, int K1, const bf16* __restrict__ A2, int K2,
    const bf16* __restrict__ Bt, int ldBt, int M,
    const bf16* __restrict__ bias1, const bf16* __restrict__ bias2,
    const bf16* __restrict__ hadd, bf16* __restrict__ outb,
    float* __restrict__ outf)
{
  constexpr int LDA = 40;
  __shared__ __align__(16) bf16 As[64 * LDA];    //  5120 B
  __shared__ __align__(16) bf16 Bs[128 * LDA];   // 10240 B

  const int tid  = threadIdx.x;
  const int col0 = blockIdx.x * 128;             // x = col tile (adjacent blocks share A panel)
  const int row0 = blockIdx.y * 64;
  const int lane = tid & 63;
  const int wave = tid >> 6;
  const int wm   = wave & 1, wn = wave >> 1;     // wm: 32-row half, wn: 64-col half
  const int ln   = lane & 15, quad = lane >> 4;
  const int K    = K1 + K2;

  f32x4 acc[2][4] = {};

  for (int k0 = 0; k0 < K; k0 += 32) {
    // 768 chunks of 8 bf16 (16B): [0,256)=A (64 rows x 4), [256,768)=B (128 rows x 4)
    #pragma unroll
    for (int rep = 0; rep < 3; ++rep) {
      const int c = tid + rep * 256;
      if (c < 256) {
        const int r  = c >> 2;
        const int kp = (c & 3) << 3;
        const int gr = min(row0 + r, M - 1);
        uint4 va;
        if (k0 < K1) va = *(const uint4*)(A1 + (size_t)gr * K1 + k0 + kp);
        else         va = *(const uint4*)(A2 + (size_t)gr * K2 + (k0 - K1) + kp);
        *(uint4*)(As + r * LDA + kp) = va;
      } else {
        const int cc = c - 256;
        const int r  = cc >> 2;
        const int kp = (cc & 3) << 3;
        *(uint4*)(Bs + r * LDA + kp) =
            *(const uint4*)(Bt + (size_t)(col0 + r) * ldBt + k0 + kp);
      }
    }
    __syncthreads();

    bf16x8 a[2], b[4];
    #pragma unroll
    for (int mi = 0; mi < 2; ++mi)
      a[mi] = *(const bf16x8*)(As + (wm * 32 + mi * 16 + ln) * LDA + quad * 8);
    #pragma unroll
    for (int ni = 0; ni < 4; ++ni)
      b[ni] = *(const bf16x8*)(Bs + (wn * 64 + ni * 16 + ln) * LDA + quad * 8);
    #pragma unroll
    for (int mi = 0; mi < 2; ++mi)
      #pragma unroll
      for (int ni = 0; ni < 4; ++ni)
        acc[mi][ni] = __builtin_amdgcn_mfma_f32_16x16x32_bf16(a[mi], b[ni], acc[mi][ni], 0, 0, 0);
    __syncthreads();
  }

  #pragma unroll
  for (int mi = 0; mi < 2; ++mi) {
    const int rbase = row0 + wm * 32 + mi * 16 + quad * 4;
    #pragma unroll
    for (int ni = 0; ni < 4; ++ni) {
      const int col = col0 + wn * 64 + ni * 16 + ln;
      float bb = __bfloat162float(bias1[col]);
      if (MODE == 0) bb += __bfloat162float(bias2[col]);
      #pragma unroll
      for (int r = 0; r < 4; ++r) {
        const int gr = rbase + r;
        if (gr >= M) continue;
        const size_t idx = (size_t)gr * 256 + col;
        float v = acc[mi][ni][r] + bb;
        if (MODE == 1) v += __bfloat162float(hadd[idx]);
        v = fmaxf(v, 0.f);
        if (MODE == 0) outb[idx] = __float2bfloat16(v);
        else           outf[idx] = v;
      }
    }
  }
}

// ---------------------------------------------------------------------------
// scan; scatter (CSR build) + fused passA0
// ---------------------------------------------------------------------------
__global__ __launch_bounds__(256) void scan_kernel(
    const int* __restrict__ deg, int* __restrict__ rowptr, int N)
{
  __shared__ int part[256];
  const int t = threadIdx.x;
  const int chunk = (N + 255) / 256;
  const int start = t * chunk;
  const int stop  = min(start + chunk, N);
  int sum = 0;
  for (int j = start; j < stop; ++j) sum += deg[j];
  part[t] = sum;
  __syncthreads();
  for (int off = 1; off < 256; off <<= 1) {
    int v = (t >= off) ? part[t - off] : 0;
    __syncthreads();
    part[t] += v;
    __syncthreads();
  }
  int base = (t == 0) ? 0 : part[t - 1];
  for (int j = start; j < stop; ++j) { rowptr[j] = base; base += deg[j]; }
  if (t == 255) rowptr[N] = part[255];
}

__global__ __launch_bounds__(256) void scatter_kernel(
    const int* __restrict__ ei, const int* __restrict__ rowptr,
    int* __restrict__ cursor, const float4* __restrict__ p0,
    const bf16* __restrict__ cvec,
    int* __restrict__ ssrc, int* __restrict__ sdst, float4* __restrict__ qs,
    int E)
{
  const int e = (int)((unsigned)blockIdx.x * 256u + threadIdx.x);
  if (e >= E) return;
  const int src = ei[e];
  const int d   = ei[E + e];
  const int pp  = rowptr[d] + atomicAdd(cursor + d, 1);
  ssrc[pp] = src;
  sdst[pp] = d;
  const float4 ps = p0[src];
  const float4 pd = p0[d];
  const float t0 = ps.x - pd.x + __bfloat162float(cvec[0]);
  const float t1 = ps.y - pd.y + __bfloat162float(cvec[1]);
  const float t2 = ps.z - pd.z + __bfloat162float(cvec[2]);
  const float t3 = ps.w - pd.w + __bfloat162float(cvec[3]);
  const float mx = fmaxf(fmaxf(t0, t1), fmaxf(t2, t3));
  const float e0 = __expf(t0 - mx), e1 = __expf(t1 - mx);
  const float e2 = __expf(t2 - mx), e3 = __expf(t3 - mx);
  const float inv = 1.f / (e0 + e1 + e2 + e3);
  qs[pp] = make_float4(e0 * inv, e1 * inv, e2 * inv, e3 * inv);
}

// passA1: q from p1 over sorted edges
__global__ __launch_bounds__(256) void passA_kernel(
    const float4* __restrict__ p, const int* __restrict__ ssrc,
    const int* __restrict__ sdst, const bf16* __restrict__ cvec,
    float4* __restrict__ qs, int E)
{
  const int e = (int)((unsigned)blockIdx.x * 256u + threadIdx.x);
  if (e >= E) return;
  const float4 ps = p[ssrc[e]];
  const float4 pd = p[sdst[e]];
  const float t0 = ps.x - pd.x + __bfloat162float(cvec[0]);
  const float t1 = ps.y - pd.y + __bfloat162float(cvec[1]);
  const float t2 = ps.z - pd.z + __bfloat162float(cvec[2]);
  const float t3 = ps.w - pd.w + __bfloat162float(cvec[3]);
  const float mx = fmaxf(fmaxf(t0, t1), fmaxf(t2, t3));
  const float e0 = __expf(t0 - mx), e1 = __expf(t1 - mx);
  const float e2 = __expf(t2 - mx), e3 = __expf(t3 - mx);
  const float inv = 1.f / (e0 + e1 + e2 + e3);
  qs[e] = make_float4(e0 * inv, e1 * inv, e2 * inv, e3 * inv);
}

// proj256: p1[i] = u1^T h0[i], one wave per node
__global__ __launch_bounds__(256) void proj256_kernel(
    const bf16* __restrict__ h, const bf16* __restrict__ u,
    float4* __restrict__ p, int N)
{
  const int node = (int)(((unsigned)blockIdx.x * 256u + threadIdx.x) >> 6);
  if (node >= N) return;
  const int lane = threadIdx.x & 63;
  const uint2 hv = *(const uint2*)(h + (size_t)node * 256 + lane * 4);
  const float d0 = bflo(hv.x), d1 = bfhi(hv.x);
  const float d2 = bflo(hv.y), d3 = bfhi(hv.y);
  const uint4 ua = *(const uint4*)(u + (size_t)lane * 16);
  const uint4 ub = *(const uint4*)(u + (size_t)lane * 16 + 8);
  float t0 = d0*bflo(ua.x) + d1*bflo(ua.z) + d2*bflo(ub.x) + d3*bflo(ub.z);
  float t1 = d0*bfhi(ua.x) + d1*bfhi(ua.z) + d2*bfhi(ub.x) + d3*bfhi(ub.z);
  float t2 = d0*bflo(ua.y) + d1*bflo(ua.w) + d2*bflo(ub.y) + d3*bflo(ub.w);
  float t3 = d0*bfhi(ua.y) + d1*bfhi(ua.w) + d2*bfhi(ub.y) + d3*bfhi(ub.w);
  #pragma unroll
  for (int off = 32; off > 0; off >>= 1) {
    t0 += __shfl_xor(t0, off);
    t1 += __shfl_xor(t1, off);
    t2 += __shfl_xor(t2, off);
    t3 += __shfl_xor(t3, off);
  }
  if (lane == 0) p[node] = make_float4(t0, t1, t2, t3);
}

// ---------------------------------------------------------------------------
// passF<CIN>: F[i][h*CIN + ch] = (1/(deg+1)) * sum_e q_eh * feat[src][ch]
// (self-loop included with q = softmax(c)). One wave per node, 4 nodes/block.
// ---------------------------------------------------------------------------
template<int CIN>
__global__ __launch_bounds__(256) void passF_kernel(
    const int* __restrict__ rowptr, const int* __restrict__ ssrc,
    const float4* __restrict__ qs, const bf16* __restrict__ feat,
    const bf16* __restrict__ cvec, bf16* __restrict__ F, int N)
{
  __shared__ int    s_src[4][64];
  __shared__ float4 s_q[4][64];
  __shared__ int    s_deg[4];

  const int t = threadIdx.x;
  const int g = t >> 6;
  const int l = t & 63;
  const int i = blockIdx.x * 4 + g;

  const int beg = (i < N) ? rowptr[i] : 0;
  const int deg = (i < N) ? rowptr[i + 1] - beg : 0;
  if (l == 0) s_deg[g] = deg;

  const float cc0 = __bfloat162float(cvec[0]), cc1 = __bfloat162float(cvec[1]);
  const float cc2 = __bfloat162float(cvec[2]), cc3 = __bfloat162float(cvec[3]);
  const float mx = fmaxf(fmaxf(cc0, cc1), fmaxf(cc2, cc3));
  const float se0 = __expf(cc0 - mx), se1 = __expf(cc1 - mx);
  const float se2 = __expf(cc2 - mx), se3 = __expf(cc3 - mx);
  const float sinv = 1.f / (se0 + se1 + se2 + se3);

  constexpr int CPL = (CIN == 128) ? 2 : 4;   // channels per lane
  float f[4][CPL];
  #pragma unroll
  for (int h = 0; h < 4; ++h)
    #pragma unroll
    for (int c = 0; c < CPL; ++c) f[h][c] = 0.f;

#define PF_BODY(SRC, QX, QY, QZ, QW)                                           \
  {                                                                            \
    if (CIN == 128) {                                                          \
      const unsigned v = *(const unsigned*)(feat + (size_t)(SRC) * 128 + l*2); \
      const float d0 = bflo(v), d1 = bfhi(v);                                  \
      f[0][0] += (QX) * d0; f[0][1] += (QX) * d1;                              \
      f[1][0] += (QY) * d0; f[1][1] += (QY) * d1;                              \
      f[2][0] += (QZ) * d0; f[2][1] += (QZ) * d1;                              \
      f[3][0] += (QW) * d0; f[3][1] += (QW) * d1;                              \
    } else {                                                                   \
      const uint2 v = *(const uint2*)(feat + (size_t)(SRC) * 256 + l*4);       \
      const float d0 = bflo(v.x), d1 = bfhi(v.x);                              \
      const float d2 = bflo(v.y), d3 = bfhi(v.y);                              \
      f[0][0] += (QX)*d0; f[0][1] += (QX)*d1; f[0][2] += (QX)*d2; f[0][3] += (QX)*d3; \
      f[1][0] += (QY)*d0; f[1][1] += (QY)*d1; f[1][2] += (QY)*d2; f[1][3] += (QY)*d3; \
      f[2][0] += (QZ)*d0; f[2][1] += (QZ)*d1; f[2][2] += (QZ)*d2; f[2][3] += (QZ)*d3; \
      f[3][0] += (QW)*d0; f[3][1] += (QW)*d1; f[3][2] += (QW)*d2; f[3][3] += (QW)*d3; \
    }                                                                          \
  }
#define PF_EDGE(EIDX)                                                          \
  {                                                                            \
    const int    src_ = s_src[g][EIDX];                                        \
    const float4 q_   = s_q[g][EIDX];                                          \
    PF_BODY(src_, q_.x, q_.y, q_.z, q_.w)                                      \
  }

  if (i < N) PF_BODY(i, se0 * sinv, se1 * sinv, se2 * sinv, se3 * sinv)

  __syncthreads();
  const int iters = (max(max(s_deg[0], s_deg[1]), max(s_deg[2], s_deg[3])) + 63) >> 6;

  for (int it = 0; it < iters; ++it) {
    const int c0  = it << 6;
    const int cnt = min(64, deg - c0);
    if (l < cnt) {
      s_src[g][l] = ssrc[beg + c0 + l];
      s_q[g][l]   = qs[beg + c0 + l];
    }
    __syncthreads();
    int e = 0;
    for (; e + 4 <= cnt; e += 4) { PF_EDGE(e) PF_EDGE(e + 1) PF_EDGE(e + 2) PF_EDGE(e + 3) }
    for (; e < cnt; ++e) PF_EDGE(e)
    __syncthreads();
  }
#undef PF_EDGE
#undef PF_BODY

  if (i >= N) return;
  const float s = 1.f / (float)(deg + 1);
  if (CIN == 128) {
    #pragma unroll
    for (int h = 0; h < 4; ++h) {
      const unsigned pk = (unsigned)f2bf(f[h][0] * s) | ((unsigned)f2bf(f[h][1] * s) << 16);
      *(unsigned*)(F + (size_t)i * 512 + h * 128 + 2 * l) = pk;
    }
  } else {
    #pragma unroll
    for (int h = 0; h < 4; ++h) {
      uint2 pk;
      pk.x = (unsigned)f2bf(f[h][0] * s) | ((unsigned)f2bf(f[h][1] * s) << 16);
      pk.y = (unsigned)f2bf(f[h][2] * s) | ((unsigned)f2bf(f[h][3] * s) << 16);
      *(uint2*)(F + (size_t)i * 1024 + h * 256 + 4 * l) = pk;
    }
  }
}

extern "C" void kernel_launch(void* const* d_in, const int* in_sizes, int n_in,
                              void* d_out, int out_size, void* d_ws, size_t ws_size,
                              hipStream_t stream)
{
  const bf16* x   = (const bf16*)d_in[0];
  const int*  ei  = (const int*)d_in[1];
  const bf16* W0  = (const bf16*)d_in[2];
  const bf16* u0  = (const bf16*)d_in[3];
  const bf16* c0  = (const bf16*)d_in[4];
  const bf16* b0  = (const bf16*)d_in[5];
  const bf16* sW0 = (const bf16*)d_in[6];
  const bf16* sb0 = (const bf16*)d_in[7];
  const bf16* W1  = (const bf16*)d_in[8];
  const bf16* u1  = (const bf16*)d_in[9];
  const bf16* c1  = (const bf16*)d_in[10];
  const bf16* b1  = (const bf16*)d_in[11];

  const int N = in_sizes[0] / 128;   // 20000
  const int E = in_sizes[1] / 2;     // 320000

  // workspace (~62 MB)
  char* ws = (char*)d_ws;
  bf16*   F      = (bf16*)ws;   ws += (size_t)N * 1024 * sizeof(bf16);  // F0 [N][512] then F1 [N][1024]
  bf16*   h0     = (bf16*)ws;   ws += (size_t)N * 256 * sizeof(bf16);
  float4* qs     = (float4*)ws; ws += (size_t)E * sizeof(float4);
  float4* p0     = (float4*)ws; ws += (size_t)N * sizeof(float4);
  float4* p1     = (float4*)ws; ws += (size_t)N * sizeof(float4);
  int*    ssrc   = (int*)ws;    ws += (size_t)E * sizeof(int);
  int*    sdst   = (int*)ws;    ws += (size_t)E * sizeof(int);
  int*    deg    = (int*)ws;    ws += (size_t)N * sizeof(int);
  int*    cursor = (int*)ws;    ws += (size_t)N * sizeof(int);
  int*    rowptr = (int*)ws;    ws += ((size_t)N + 1) * sizeof(int);
  bf16*   Btc0   = (bf16*)ws;   ws += (size_t)256 * 640 * sizeof(bf16);  // [stack_h W0 | sW0]^T
  bf16*   Bt1    = (bf16*)ws;   ws += (size_t)256 * 1024 * sizeof(bf16); // stack_h W1 ^T

  hipMemsetAsync(deg, 0, 2 * (size_t)N * sizeof(int), stream);  // deg + cursor

  const int eBlocks  = (E + 255) / 256;          // 1250
  const int gTiles   = (N + 63) / 64;            // 313 row tiles for gemm_cat
  const int nwBlocks = (N + 3) / 4;              // wave-per-node kernels

  const int b4 = 416 + eBlocks;
  const int b5 = b4 + (2 * E + 255) / 256;
  const int b6 = b5 + nwBlocks;

  // ---- setup: weight reshuffles + hist + edgecopy + proj128 ----
  prep_kernel<<<b6, 256, 0, stream>>>(x, ei, W0, sW0, W1, u0, Btc0, Bt1,
                                      deg, (float*)d_out + (size_t)N * 256, p0,
                                      N, E, b4, b5);
  scan_kernel<<<1, 256, 0, stream>>>(deg, rowptr, N);
  scatter_kernel<<<eBlocks, 256, 0, stream>>>(ei, rowptr, cursor, p0, c0,
                                              ssrc, sdst, qs, E);

  // ---- Block 0: F0 = scaled scatter of x; h0 = relu([F0|x]@Btc0 + b0+sb0) ----
  passF_kernel<128><<<nwBlocks, 256, 0, stream>>>(rowptr, ssrc, qs, x, c0, F, N);
  gemm_cat_kernel<0><<<dim3(2, gTiles), 256, 0, stream>>>(
      F, 512, x, 128, Btc0, 640, N, b0, sb0, nullptr, h0, nullptr);

  // ---- Block 1: p1; q1; F1 = scaled scatter of h0; out = relu(F1@Bt1 + b1 + h0) ----
  proj256_kernel<<<nwBlocks, 256, 0, stream>>>(h0, u1, p1, N);
  passA_kernel<<<eBlocks, 256, 0, stream>>>(p1, ssrc, sdst, c1, qs, E);
  passF_kernel<256><<<nwBlocks, 256, 0, stream>>>(rowptr, ssrc, qs, h0, c1, F, N);
  gemm_cat_kernel<1><<<dim3(2, gTiles), 256, 0, stream>>>(
      F, 1024, nullptr, 0, Bt1, 1024, N, b1, nullptr, h0, nullptr, (float*)d_out);
}